// Round 1
// baseline (653.111 us; speedup 1.0000x reference)
//
#include <hip/hip_runtime.h>
#include <hip/hip_bf16.h>
#include <stdint.h>

#define FEATS 128
#define SCAN_B 256
#define SCAN_ITEMS 4
#define SCAN_TILE (SCAN_B * SCAN_ITEMS)
#define SCAN2_B 1024
#define GM 64
#define HPAD 132

// ---------------- CSR build ----------------

__global__ void hist_kernel(const int* __restrict__ dst, int* __restrict__ deg, int E) {
  int i = blockIdx.x * blockDim.x + threadIdx.x;
  int stride = gridDim.x * blockDim.x;
  for (; i < E; i += stride) atomicAdd(&deg[dst[i]], 1);
}

__global__ void scan1_kernel(const int* __restrict__ deg, int* __restrict__ off,
                             int* __restrict__ blockSums, int N) {
  __shared__ int s[SCAN_B];
  int t = threadIdx.x;
  int base = blockIdx.x * SCAN_TILE + t * SCAN_ITEMS;
  int v[SCAN_ITEMS];
  int tsum = 0;
#pragma unroll
  for (int j = 0; j < SCAN_ITEMS; ++j) {
    int i = base + j;
    v[j] = (i < N) ? deg[i] : 0;
    tsum += v[j];
  }
  s[t] = tsum;
  __syncthreads();
  for (int o = 1; o < SCAN_B; o <<= 1) {
    int add = (t >= o) ? s[t - o] : 0;
    __syncthreads();
    s[t] += add;
    __syncthreads();
  }
  int run = s[t] - tsum;  // exclusive prefix of this thread within block
#pragma unroll
  for (int j = 0; j < SCAN_ITEMS; ++j) {
    int i = base + j;
    if (i < N) off[i] = run;
    run += v[j];
  }
  if (t == SCAN_B - 1) blockSums[blockIdx.x] = run;  // block total
}

__global__ void scan2_kernel(const int* __restrict__ blockSums, int* __restrict__ blockOff, int nb) {
  __shared__ int s[SCAN2_B];
  int t = threadIdx.x;
  int v = (t < nb) ? blockSums[t] : 0;
  s[t] = v;
  __syncthreads();
  for (int o = 1; o < SCAN2_B; o <<= 1) {
    int add = (t >= o) ? s[t - o] : 0;
    __syncthreads();
    s[t] += add;
    __syncthreads();
  }
  if (t < nb) blockOff[t] = s[t] - v;  // exclusive
}

__global__ void scan3_kernel(int* __restrict__ off, const int* __restrict__ blockOff,
                             int* __restrict__ cursor, int N) {
  int i = blockIdx.x * blockDim.x + threadIdx.x;
  int stride = gridDim.x * blockDim.x;
  for (; i < N; i += stride) {
    int o = off[i] + blockOff[i / SCAN_TILE];
    off[i] = o;
    cursor[i] = o;
  }
}

__global__ void scatter_kernel(const int* __restrict__ src, const int* __restrict__ dst,
                               int* __restrict__ cursor, int* __restrict__ srcSorted, int E) {
  int i = blockIdx.x * blockDim.x + threadIdx.x;
  int stride = gridDim.x * blockDim.x;
  for (; i < E; i += stride) {
    int p = atomicAdd(&cursor[dst[i]], 1);
    srcSorted[p] = src[i];
  }
}

// ---------------- mean aggregation: one wave per node, gather-only ----------------

__global__ void agg_kernel(const float* __restrict__ X, const int* __restrict__ srcSorted,
                           const int* __restrict__ off, const int* __restrict__ deg,
                           float* __restrict__ A, int N) {
  int wid = (int)((blockIdx.x * (unsigned)blockDim.x + threadIdx.x) >> 6);
  int lane = threadIdx.x & 63;
  if (wid >= N) return;
  int start = off[wid];
  int d = deg[wid];
  float ax = 0.f, ay = 0.f;
  for (int i = 0; i < d; ++i) {
    int s = srcSorted[start + i];
    float2 v = *(const float2*)&X[(size_t)s * FEATS + lane * 2];
    ax += v.x;
    ay += v.y;
  }
  float scale = (d > 0) ? (1.0f / (float)d) : 0.0f;
  float2 r;
  r.x = ax * scale;
  r.y = ay * scale;
  *(float2*)&A[(size_t)wid * FEATS + lane * 2] = r;
}

// ---------------- fused (x + A) @ W + b (+relu), f32 vector ----------------

template <int RELU>
__global__ __launch_bounds__(256) void gemm_kernel(const float* __restrict__ X,
                                                   const float* __restrict__ A,
                                                   const float* __restrict__ W,
                                                   const float* __restrict__ bias,
                                                   float* __restrict__ out, int N) {
  __shared__ float hs[GM * HPAD];
  int t = threadIdx.x;
  int vbase = blockIdx.x * GM;

  // stage h = x + A tile into LDS
  for (int i = t; i < GM * 32; i += 256) {
    int row = i >> 5;
    int c4 = (i & 31) * 4;
    int v = vbase + row;
    float4 h4;
    if (v < N) {
      float4 xv = *(const float4*)&X[(size_t)v * FEATS + c4];
      float4 av = *(const float4*)&A[(size_t)v * FEATS + c4];
      h4 = make_float4(xv.x + av.x, xv.y + av.y, xv.z + av.z, xv.w + av.w);
    } else {
      h4 = make_float4(0.f, 0.f, 0.f, 0.f);
    }
    *(float4*)&hs[row * HPAD + c4] = h4;
  }
  __syncthreads();

  int tx = t & 31;
  int ty = t >> 5;  // 0..7, each ty owns 8 rows
  int j0 = tx * 4;

  float acc[8][4];
#pragma unroll
  for (int r = 0; r < 8; ++r)
#pragma unroll
    for (int c = 0; c < 4; ++c) acc[r][c] = 0.f;

  for (int k = 0; k < FEATS; k += 4) {
    float4 w0 = *(const float4*)&W[(size_t)(k + 0) * FEATS + j0];
    float4 w1 = *(const float4*)&W[(size_t)(k + 1) * FEATS + j0];
    float4 w2 = *(const float4*)&W[(size_t)(k + 2) * FEATS + j0];
    float4 w3 = *(const float4*)&W[(size_t)(k + 3) * FEATS + j0];
#pragma unroll
    for (int rr = 0; rr < 8; ++rr) {
      float4 h4 = *(const float4*)&hs[(ty * 8 + rr) * HPAD + k];
      acc[rr][0] += h4.x * w0.x + h4.y * w1.x + h4.z * w2.x + h4.w * w3.x;
      acc[rr][1] += h4.x * w0.y + h4.y * w1.y + h4.z * w2.y + h4.w * w3.y;
      acc[rr][2] += h4.x * w0.z + h4.y * w1.z + h4.z * w2.z + h4.w * w3.z;
      acc[rr][3] += h4.x * w0.w + h4.y * w1.w + h4.z * w2.w + h4.w * w3.w;
    }
  }

  float4 b4 = *(const float4*)&bias[j0];
#pragma unroll
  for (int rr = 0; rr < 8; ++rr) {
    int v = vbase + ty * 8 + rr;
    if (v < N) {
      float4 o;
      o.x = acc[rr][0] + b4.x;
      o.y = acc[rr][1] + b4.y;
      o.z = acc[rr][2] + b4.z;
      o.w = acc[rr][3] + b4.w;
      if (RELU) {
        o.x = fmaxf(o.x, 0.f);
        o.y = fmaxf(o.y, 0.f);
        o.z = fmaxf(o.z, 0.f);
        o.w = fmaxf(o.w, 0.f);
      }
      *(float4*)&out[(size_t)v * FEATS + j0] = o;
    }
  }
}

// ---------------- launcher ----------------

extern "C" void kernel_launch(void* const* d_in, const int* in_sizes, int n_in,
                              void* d_out, int out_size, void* d_ws, size_t ws_size,
                              hipStream_t stream) {
  const float* X = (const float*)d_in[0];
  const int* src = (const int*)d_in[1];
  const int* dst = (const int*)d_in[2];
  const float* W1 = (const float*)d_in[3];
  const float* b1 = (const float*)d_in[4];
  const float* W2 = (const float*)d_in[5];
  const float* b2 = (const float*)d_in[6];
  float* out = (float*)d_out;

  int N = in_sizes[0] / FEATS;
  int E = in_sizes[1];
  int nb = (N + SCAN_TILE - 1) / SCAN_TILE;

  // bump-allocate workspace (aligned 256B)
  char* ws = (char*)d_ws;
  auto alloc = [&](size_t bytes) -> char* {
    char* p = ws;
    ws += (bytes + 255) & ~(size_t)255;
    return p;
  };
  int* deg = (int*)alloc((size_t)N * 4);
  int* off = (int*)alloc((size_t)N * 4);
  int* cursor = (int*)alloc((size_t)N * 4);
  int* blockSums = (int*)alloc((size_t)nb * 4);
  int* blockOff = (int*)alloc((size_t)nb * 4);
  int* srcSorted = (int*)alloc((size_t)E * 4);
  float* A = (float*)alloc((size_t)N * FEATS * 4);

  // ---- CSR build ----
  hipMemsetAsync(deg, 0, (size_t)N * 4, stream);
  hist_kernel<<<(E + 255) / 256, 256, 0, stream>>>(dst, deg, E);
  scan1_kernel<<<nb, SCAN_B, 0, stream>>>(deg, off, blockSums, N);
  scan2_kernel<<<1, SCAN2_B, 0, stream>>>(blockSums, blockOff, nb);
  scan3_kernel<<<(N + 255) / 256, 256, 0, stream>>>(off, blockOff, cursor, N);
  scatter_kernel<<<(E + 255) / 256, 256, 0, stream>>>(src, dst, cursor, srcSorted, E);

  int aggBlocks = (N + 3) / 4;  // 4 waves (nodes) per 256-thread block
  int gb = (N + GM - 1) / GM;

  // ---- layer 1: A = mean_agg(X); out = relu((X + A) @ W1 + b1) ----
  agg_kernel<<<aggBlocks, 256, 0, stream>>>(X, srcSorted, off, deg, A, N);
  gemm_kernel<1><<<gb, 256, 0, stream>>>(X, A, W1, b1, out, N);

  // ---- layer 2: A = mean_agg(out); out = (out + A) @ W2 + b2  (in-place, tile-local) ----
  agg_kernel<<<aggBlocks, 256, 0, stream>>>(out, srcSorted, off, deg, A, N);
  gemm_kernel<0><<<gb, 256, 0, stream>>>(out, A, W2, b2, out, N);
}

// Round 2
// 483.731 us; speedup vs baseline: 1.3502x; 1.3502x over previous
//
#include <hip/hip_runtime.h>
#include <hip/hip_bf16.h>
#include <stdint.h>

#define FEATS 128
#define SCAN_B 256
#define SCAN_ITEMS 4
#define SCAN_TILE (SCAN_B * SCAN_ITEMS)
#define SCAN2_B 1024
#define GM 64
#define HPAD 132

// ---------------- helpers ----------------

__device__ inline uint32_t f2bf(float f) {  // RTNE f32 -> bf16 (low 16 bits)
  uint32_t x = __float_as_uint(f);
  uint32_t r = ((x >> 16) & 1u) + 0x7fffu;
  return (x + r) >> 16;
}
__device__ inline float bflo(uint32_t u) { return __uint_as_float(u << 16); }
__device__ inline float bfhi(uint32_t u) { return __uint_as_float(u & 0xffff0000u); }

// ---------------- CSR build ----------------

__global__ void hist_kernel(const int* __restrict__ dst, int* __restrict__ deg, int E) {
  int i = blockIdx.x * blockDim.x + threadIdx.x;
  int stride = gridDim.x * blockDim.x;
  for (; i < E; i += stride) atomicAdd(&deg[dst[i]], 1);
}

__global__ void scan1_kernel(const int* __restrict__ deg, int* __restrict__ off,
                             int* __restrict__ blockSums, int N) {
  __shared__ int s[SCAN_B];
  int t = threadIdx.x;
  int base = blockIdx.x * SCAN_TILE + t * SCAN_ITEMS;
  int v[SCAN_ITEMS];
  int tsum = 0;
#pragma unroll
  for (int j = 0; j < SCAN_ITEMS; ++j) {
    int i = base + j;
    v[j] = (i < N) ? deg[i] : 0;
    tsum += v[j];
  }
  s[t] = tsum;
  __syncthreads();
  for (int o = 1; o < SCAN_B; o <<= 1) {
    int add = (t >= o) ? s[t - o] : 0;
    __syncthreads();
    s[t] += add;
    __syncthreads();
  }
  int run = s[t] - tsum;
#pragma unroll
  for (int j = 0; j < SCAN_ITEMS; ++j) {
    int i = base + j;
    if (i < N) off[i] = run;
    run += v[j];
  }
  if (t == SCAN_B - 1) blockSums[blockIdx.x] = run;
}

__global__ void scan2_kernel(const int* __restrict__ blockSums, int* __restrict__ blockOff, int nb) {
  __shared__ int s[SCAN2_B];
  int t = threadIdx.x;
  int v = (t < nb) ? blockSums[t] : 0;
  s[t] = v;
  __syncthreads();
  for (int o = 1; o < SCAN2_B; o <<= 1) {
    int add = (t >= o) ? s[t - o] : 0;
    __syncthreads();
    s[t] += add;
    __syncthreads();
  }
  if (t < nb) blockOff[t] = s[t] - v;
}

__global__ void scan3_kernel(int* __restrict__ off, const int* __restrict__ blockOff,
                             int* __restrict__ cursor, int N) {
  int i = blockIdx.x * blockDim.x + threadIdx.x;
  int stride = gridDim.x * blockDim.x;
  for (; i < N; i += stride) {
    int o = off[i] + blockOff[i / SCAN_TILE];
    off[i] = o;
    cursor[i] = o;
  }
}

__global__ void scatter_kernel(const int* __restrict__ src, const int* __restrict__ dst,
                               int* __restrict__ cursor, int* __restrict__ srcSorted, int E) {
  int i = blockIdx.x * blockDim.x + threadIdx.x;
  int stride = gridDim.x * blockDim.x;
  for (; i < E; i += stride) {
    int p = atomicAdd(&cursor[dst[i]], 1);
    srcSorted[p] = src[i];
  }
}

// ---------------- f32 -> bf16 cast of the whole feature matrix ----------------

__global__ void cast_kernel(const float* __restrict__ X, uint32_t* __restrict__ Xh, int n) {
  int i = blockIdx.x * blockDim.x + threadIdx.x;  // n = N*64 packed uints
  if (i >= n) return;
  float2 v = ((const float2*)X)[i];
  Xh[i] = f2bf(v.x) | (f2bf(v.y) << 16);
}

// ---------------- mean aggregation: one wave per node, bf16 gather, 4x unroll ----------------

__global__ void agg_kernel(const uint32_t* __restrict__ Xh, const int* __restrict__ srcSorted,
                           const int* __restrict__ off, const int* __restrict__ deg,
                           uint32_t* __restrict__ Ah, int N) {
  int wid = (int)((blockIdx.x * (unsigned)blockDim.x + threadIdx.x) >> 6);
  int lane = threadIdx.x & 63;
  if (wid >= N) return;
  int start = off[wid];
  int d = deg[wid];
  const uint32_t* Xl = Xh + lane;  // row stride = 64 uints (128 bf16)
  float a0 = 0.f, a1 = 0.f, b0 = 0.f, b1 = 0.f;
  float c0 = 0.f, c1 = 0.f, e0 = 0.f, e1 = 0.f;
  int i = 0;
  for (; i + 4 <= d; i += 4) {
    int s0 = srcSorted[start + i + 0];
    int s1 = srcSorted[start + i + 1];
    int s2 = srcSorted[start + i + 2];
    int s3 = srcSorted[start + i + 3];
    uint32_t u0 = Xl[(size_t)s0 << 6];
    uint32_t u1 = Xl[(size_t)s1 << 6];
    uint32_t u2 = Xl[(size_t)s2 << 6];
    uint32_t u3 = Xl[(size_t)s3 << 6];
    a0 += bflo(u0); a1 += bfhi(u0);
    b0 += bflo(u1); b1 += bfhi(u1);
    c0 += bflo(u2); c1 += bfhi(u2);
    e0 += bflo(u3); e1 += bfhi(u3);
  }
  for (; i < d; ++i) {
    int s = srcSorted[start + i];
    uint32_t u = Xl[(size_t)s << 6];
    a0 += bflo(u); a1 += bfhi(u);
  }
  float s0 = (a0 + b0) + (c0 + e0);
  float s1 = (a1 + b1) + (c1 + e1);
  float scale = (d > 0) ? (1.0f / (float)d) : 0.0f;
  Ah[(size_t)wid * 64 + lane] = f2bf(s0 * scale) | (f2bf(s1 * scale) << 16);
}

// ---------------- fused (x + A) @ W + b (+relu), f32 vector; optional bf16 h-copy out ----------------

template <int RELU, int WRITEH>
__global__ __launch_bounds__(256) void gemm_kernel(const float* __restrict__ X,
                                                   const uint32_t* __restrict__ Ah,
                                                   const float* __restrict__ W,
                                                   const float* __restrict__ bias,
                                                   float* __restrict__ out,
                                                   uint32_t* __restrict__ Hh, int N) {
  __shared__ float hs[GM * HPAD];
  int t = threadIdx.x;
  int vbase = blockIdx.x * GM;

  // stage h = x + A tile into LDS
  for (int i = t; i < GM * 32; i += 256) {
    int row = i >> 5;
    int c4 = (i & 31) * 4;
    int v = vbase + row;
    float4 h4;
    if (v < N) {
      float4 xv = *(const float4*)&X[(size_t)v * FEATS + c4];
      uint2 au = *(const uint2*)&Ah[(size_t)v * 64 + (c4 >> 1)];
      h4.x = xv.x + bflo(au.x);
      h4.y = xv.y + bfhi(au.x);
      h4.z = xv.z + bflo(au.y);
      h4.w = xv.w + bfhi(au.y);
    } else {
      h4 = make_float4(0.f, 0.f, 0.f, 0.f);
    }
    *(float4*)&hs[row * HPAD + c4] = h4;
  }
  __syncthreads();

  int tx = t & 31;
  int ty = t >> 5;  // 0..7, each ty owns 8 rows
  int j0 = tx * 4;

  float acc[8][4];
#pragma unroll
  for (int r = 0; r < 8; ++r)
#pragma unroll
    for (int c = 0; c < 4; ++c) acc[r][c] = 0.f;

  for (int k = 0; k < FEATS; k += 4) {
    float4 w0 = *(const float4*)&W[(size_t)(k + 0) * FEATS + j0];
    float4 w1 = *(const float4*)&W[(size_t)(k + 1) * FEATS + j0];
    float4 w2 = *(const float4*)&W[(size_t)(k + 2) * FEATS + j0];
    float4 w3 = *(const float4*)&W[(size_t)(k + 3) * FEATS + j0];
#pragma unroll
    for (int rr = 0; rr < 8; ++rr) {
      float4 h4 = *(const float4*)&hs[(ty * 8 + rr) * HPAD + k];
      acc[rr][0] += h4.x * w0.x + h4.y * w1.x + h4.z * w2.x + h4.w * w3.x;
      acc[rr][1] += h4.x * w0.y + h4.y * w1.y + h4.z * w2.y + h4.w * w3.y;
      acc[rr][2] += h4.x * w0.z + h4.y * w1.z + h4.z * w2.z + h4.w * w3.z;
      acc[rr][3] += h4.x * w0.w + h4.y * w1.w + h4.z * w2.w + h4.w * w3.w;
    }
  }

  float4 b4 = *(const float4*)&bias[j0];
#pragma unroll
  for (int rr = 0; rr < 8; ++rr) {
    int v = vbase + ty * 8 + rr;
    if (v < N) {
      float4 o;
      o.x = acc[rr][0] + b4.x;
      o.y = acc[rr][1] + b4.y;
      o.z = acc[rr][2] + b4.z;
      o.w = acc[rr][3] + b4.w;
      if (RELU) {
        o.x = fmaxf(o.x, 0.f);
        o.y = fmaxf(o.y, 0.f);
        o.z = fmaxf(o.z, 0.f);
        o.w = fmaxf(o.w, 0.f);
      }
      *(float4*)&out[(size_t)v * FEATS + j0] = o;
      if (WRITEH) {
        uint2 hu;
        hu.x = f2bf(o.x) | (f2bf(o.y) << 16);
        hu.y = f2bf(o.z) | (f2bf(o.w) << 16);
        *(uint2*)&Hh[(size_t)v * 64 + (j0 >> 1)] = hu;
      }
    }
  }
}

// ---------------- launcher ----------------

extern "C" void kernel_launch(void* const* d_in, const int* in_sizes, int n_in,
                              void* d_out, int out_size, void* d_ws, size_t ws_size,
                              hipStream_t stream) {
  const float* X = (const float*)d_in[0];
  const int* src = (const int*)d_in[1];
  const int* dst = (const int*)d_in[2];
  const float* W1 = (const float*)d_in[3];
  const float* b1 = (const float*)d_in[4];
  const float* W2 = (const float*)d_in[5];
  const float* b2 = (const float*)d_in[6];
  float* out = (float*)d_out;

  int N = in_sizes[0] / FEATS;
  int E = in_sizes[1];
  int nb = (N + SCAN_TILE - 1) / SCAN_TILE;

  char* ws = (char*)d_ws;
  auto alloc = [&](size_t bytes) -> char* {
    char* p = ws;
    ws += (bytes + 255) & ~(size_t)255;
    return p;
  };
  int* deg = (int*)alloc((size_t)N * 4);
  int* off = (int*)alloc((size_t)N * 4);
  int* cursor = (int*)alloc((size_t)N * 4);
  int* blockSums = (int*)alloc((size_t)nb * 4);
  int* blockOff = (int*)alloc((size_t)nb * 4);
  int* srcSorted = (int*)alloc((size_t)E * 4);
  uint32_t* Xh = (uint32_t*)alloc((size_t)N * 64 * 4);  // bf16 feature matrix (gather source)
  uint32_t* Ah = (uint32_t*)alloc((size_t)N * 64 * 4);  // bf16 aggregate

  // ---- CSR build ----
  hipMemsetAsync(deg, 0, (size_t)N * 4, stream);
  hist_kernel<<<(E + 255) / 256, 256, 0, stream>>>(dst, deg, E);
  scan1_kernel<<<nb, SCAN_B, 0, stream>>>(deg, off, blockSums, N);
  scan2_kernel<<<1, SCAN2_B, 0, stream>>>(blockSums, blockOff, nb);
  scan3_kernel<<<(N + 255) / 256, 256, 0, stream>>>(off, blockOff, cursor, N);
  scatter_kernel<<<(E + 255) / 256, 256, 0, stream>>>(src, dst, cursor, srcSorted, E);

  // ---- bf16 copy of input features ----
  int ncast = N * 64;
  cast_kernel<<<(ncast + 255) / 256, 256, 0, stream>>>(X, Xh, ncast);

  int aggBlocks = (N + 3) / 4;
  int gb = (N + GM - 1) / GM;

  // ---- layer 1 ----
  agg_kernel<<<aggBlocks, 256, 0, stream>>>(Xh, srcSorted, off, deg, Ah, N);
  gemm_kernel<1, 1><<<gb, 256, 0, stream>>>(X, Ah, W1, b1, out, Xh, N);  // also emits bf16 h1 into Xh

  // ---- layer 2 ----
  agg_kernel<<<aggBlocks, 256, 0, stream>>>(Xh, srcSorted, off, deg, Ah, N);
  gemm_kernel<0, 0><<<gb, 256, 0, stream>>>(out, Ah, W2, b2, out, nullptr, N);
}

// Round 3
// 393.228 us; speedup vs baseline: 1.6609x; 1.2302x over previous
//
#include <hip/hip_runtime.h>
#include <hip/hip_bf16.h>
#include <stdint.h>

#define FEATS 128
#define SCAN_B 256
#define SCAN_ITEMS 4
#define SCAN_TILE (SCAN_B * SCAN_ITEMS)
#define SCAN2_B 1024
#define GM 64
#define HPAD 132
#define NB_MAX 512        // max buckets (supports N <= 131072)
#define PS_B 1024         // pair-scatter block threads
#define PS_EPT 16         // edges per thread
#define PS_CHUNK (PS_B * PS_EPT)

// ---------------- helpers ----------------

__device__ inline uint32_t f2bf(float f) {  // RTNE f32 -> bf16 (low 16 bits)
  uint32_t x = __float_as_uint(f);
  uint32_t r = ((x >> 16) & 1u) + 0x7fffu;
  return (x + r) >> 16;
}
__device__ inline float bflo(uint32_t u) { return __uint_as_float(u << 16); }
__device__ inline float bfhi(uint32_t u) { return __uint_as_float(u & 0xffff0000u); }

// ---------------- CSR build ----------------

__global__ void hist_kernel(const int* __restrict__ dst, int* __restrict__ deg, int E) {
  int i = blockIdx.x * blockDim.x + threadIdx.x;
  int stride = gridDim.x * blockDim.x;
  for (; i < E; i += stride) atomicAdd(&deg[dst[i]], 1);
}

__global__ void scan1_kernel(const int* __restrict__ deg, int* __restrict__ off,
                             int* __restrict__ blockSums, int N) {
  __shared__ int s[SCAN_B];
  int t = threadIdx.x;
  int base = blockIdx.x * SCAN_TILE + t * SCAN_ITEMS;
  int v[SCAN_ITEMS];
  int tsum = 0;
#pragma unroll
  for (int j = 0; j < SCAN_ITEMS; ++j) {
    int i = base + j;
    v[j] = (i < N) ? deg[i] : 0;
    tsum += v[j];
  }
  s[t] = tsum;
  __syncthreads();
  for (int o = 1; o < SCAN_B; o <<= 1) {
    int add = (t >= o) ? s[t - o] : 0;
    __syncthreads();
    s[t] += add;
    __syncthreads();
  }
  int run = s[t] - tsum;
#pragma unroll
  for (int j = 0; j < SCAN_ITEMS; ++j) {
    int i = base + j;
    if (i < N) off[i] = run;
    run += v[j];
  }
  if (t == SCAN_B - 1) blockSums[blockIdx.x] = run;
}

__global__ void scan2_kernel(const int* __restrict__ blockSums, int* __restrict__ blockOff, int nb) {
  __shared__ int s[SCAN2_B];
  int t = threadIdx.x;
  int v = (t < nb) ? blockSums[t] : 0;
  s[t] = v;
  __syncthreads();
  for (int o = 1; o < SCAN2_B; o <<= 1) {
    int add = (t >= o) ? s[t - o] : 0;
    __syncthreads();
    s[t] += add;
    __syncthreads();
  }
  if (t < nb) blockOff[t] = s[t] - v;
}

__global__ void scan3_kernel(int* __restrict__ off, const int* __restrict__ blockOff, int N) {
  int i = blockIdx.x * blockDim.x + threadIdx.x;
  int stride = gridDim.x * blockDim.x;
  for (; i < N; i += stride) off[i] = off[i] + blockOff[i / SCAN_TILE];
}

// bucketCursor[b] = off[b*256]  (start of bucket b's CSR range)
__global__ void initcur_kernel(const int* __restrict__ off, int* __restrict__ bucketCursor,
                               int N, int NB) {
  int b = threadIdx.x;
  if (b < NB) bucketCursor[b] = off[b * 256];
}

// ---- pass 2: multisplit (src,dst) pairs into dst-page buckets, line-dense runs ----
__global__ __launch_bounds__(PS_B) void pairscatter_kernel(const int* __restrict__ src,
                                                           const int* __restrict__ dst,
                                                           int* __restrict__ bucketCursor,
                                                           uint2* __restrict__ pairs, int E) {
  __shared__ int hist[NB_MAX];
  __shared__ int rank[NB_MAX];
  __shared__ int res[NB_MAX];
  int t = threadIdx.x;
  int base = blockIdx.x * PS_CHUNK;

  if (t < NB_MAX) {
    hist[t] = 0;
    rank[t] = 0;
  }
  __syncthreads();

  int sr[PS_EPT], dr[PS_EPT];
#pragma unroll
  for (int j = 0; j < PS_EPT; ++j) {
    int i = base + j * PS_B + t;
    if (i < E) {
      sr[j] = src[i];
      dr[j] = dst[i];
      atomicAdd(&hist[dr[j] >> 8], 1);
    } else {
      dr[j] = -1;
    }
  }
  __syncthreads();

  if (t < NB_MAX) {
    int h = hist[t];
    res[t] = h ? atomicAdd(&bucketCursor[t], h) : 0;
  }
  __syncthreads();

#pragma unroll
  for (int j = 0; j < PS_EPT; ++j) {
    if (dr[j] >= 0) {
      int b = dr[j] >> 8;
      int r = atomicAdd(&rank[b], 1);
      pairs[(size_t)(res[b] + r)] = make_uint2((uint32_t)sr[j], (uint32_t)dr[j]);
    }
  }
}

// ---- pass 3: within-bucket final scatter; node cursors in LDS, stores page-local ----
__global__ __launch_bounds__(256) void finalscatter_kernel(const uint2* __restrict__ pairs,
                                                           const int* __restrict__ off,
                                                           int* __restrict__ srcSorted,
                                                           int N, int E) {
  __shared__ int cur[256];
  int b = blockIdx.x;
  int t = threadIdx.x;
  int node = b * 256 + t;
  cur[t] = (node < N) ? off[node] : 0;
  __syncthreads();

  int bs = off[b * 256];
  int nxt = (b + 1) * 256;
  int be = (nxt < N) ? off[nxt] : E;
  for (int i = bs + t; i < be; i += 256) {
    uint2 p = pairs[i];
    int pos = atomicAdd(&cur[p.y & 255], 1);
    srcSorted[pos] = (int)p.x;
  }
}

// ---------------- f32 -> bf16 cast of the whole feature matrix ----------------

__global__ void cast_kernel(const float* __restrict__ X, uint32_t* __restrict__ Xh, int n) {
  int i = blockIdx.x * blockDim.x + threadIdx.x;  // n = N*64 packed uints
  if (i >= n) return;
  float2 v = ((const float2*)X)[i];
  Xh[i] = f2bf(v.x) | (f2bf(v.y) << 16);
}

// ---------------- mean aggregation: one wave per node, bf16 gather, 8x unroll ----------------

__global__ void agg_kernel(const uint32_t* __restrict__ Xh, const int* __restrict__ srcSorted,
                           const int* __restrict__ off, const int* __restrict__ deg,
                           uint32_t* __restrict__ Ah, int N) {
  int wid = (int)((blockIdx.x * (unsigned)blockDim.x + threadIdx.x) >> 6);
  int lane = threadIdx.x & 63;
  if (wid >= N) return;
  int start = off[wid];
  int d = deg[wid];
  const uint32_t* Xl = Xh + lane;  // row stride = 64 uints (128 bf16)
  float a0 = 0.f, a1 = 0.f, b0 = 0.f, b1 = 0.f;
  float c0 = 0.f, c1 = 0.f, e0 = 0.f, e1 = 0.f;
  int i = 0;
  for (; i + 8 <= d; i += 8) {
    int s0 = srcSorted[start + i + 0];
    int s1 = srcSorted[start + i + 1];
    int s2 = srcSorted[start + i + 2];
    int s3 = srcSorted[start + i + 3];
    int s4 = srcSorted[start + i + 4];
    int s5 = srcSorted[start + i + 5];
    int s6 = srcSorted[start + i + 6];
    int s7 = srcSorted[start + i + 7];
    uint32_t u0 = Xl[(size_t)s0 << 6];
    uint32_t u1 = Xl[(size_t)s1 << 6];
    uint32_t u2 = Xl[(size_t)s2 << 6];
    uint32_t u3 = Xl[(size_t)s3 << 6];
    uint32_t u4 = Xl[(size_t)s4 << 6];
    uint32_t u5 = Xl[(size_t)s5 << 6];
    uint32_t u6 = Xl[(size_t)s6 << 6];
    uint32_t u7 = Xl[(size_t)s7 << 6];
    a0 += bflo(u0); a1 += bfhi(u0);
    b0 += bflo(u1); b1 += bfhi(u1);
    c0 += bflo(u2); c1 += bfhi(u2);
    e0 += bflo(u3); e1 += bfhi(u3);
    a0 += bflo(u4); a1 += bfhi(u4);
    b0 += bflo(u5); b1 += bfhi(u5);
    c0 += bflo(u6); c1 += bfhi(u6);
    e0 += bflo(u7); e1 += bfhi(u7);
  }
  for (; i < d; ++i) {
    int s = srcSorted[start + i];
    uint32_t u = Xl[(size_t)s << 6];
    a0 += bflo(u); a1 += bfhi(u);
  }
  float s0 = (a0 + b0) + (c0 + e0);
  float s1 = (a1 + b1) + (c1 + e1);
  float scale = (d > 0) ? (1.0f / (float)d) : 0.0f;
  Ah[(size_t)wid * 64 + lane] = f2bf(s0 * scale) | (f2bf(s1 * scale) << 16);
}

// ---------------- fused (x + A) @ W + b (+relu), f32 vector; optional bf16 h-copy out ----------------

template <int RELU, int WRITEH>
__global__ __launch_bounds__(256) void gemm_kernel(const float* __restrict__ X,
                                                   const uint32_t* __restrict__ Ah,
                                                   const float* __restrict__ W,
                                                   const float* __restrict__ bias,
                                                   float* __restrict__ out,
                                                   uint32_t* __restrict__ Hh, int N) {
  __shared__ float hs[GM * HPAD];
  int t = threadIdx.x;
  int vbase = blockIdx.x * GM;

  // stage h = x + A tile into LDS
  for (int i = t; i < GM * 32; i += 256) {
    int row = i >> 5;
    int c4 = (i & 31) * 4;
    int v = vbase + row;
    float4 h4;
    if (v < N) {
      float4 xv = *(const float4*)&X[(size_t)v * FEATS + c4];
      uint2 au = *(const uint2*)&Ah[(size_t)v * 64 + (c4 >> 1)];
      h4.x = xv.x + bflo(au.x);
      h4.y = xv.y + bfhi(au.x);
      h4.z = xv.z + bflo(au.y);
      h4.w = xv.w + bfhi(au.y);
    } else {
      h4 = make_float4(0.f, 0.f, 0.f, 0.f);
    }
    *(float4*)&hs[row * HPAD + c4] = h4;
  }
  __syncthreads();

  int tx = t & 31;
  int ty = t >> 5;  // 0..7, each ty owns 8 rows
  int j0 = tx * 4;

  float acc[8][4];
#pragma unroll
  for (int r = 0; r < 8; ++r)
#pragma unroll
    for (int c = 0; c < 4; ++c) acc[r][c] = 0.f;

  for (int k = 0; k < FEATS; k += 4) {
    float4 w0 = *(const float4*)&W[(size_t)(k + 0) * FEATS + j0];
    float4 w1 = *(const float4*)&W[(size_t)(k + 1) * FEATS + j0];
    float4 w2 = *(const float4*)&W[(size_t)(k + 2) * FEATS + j0];
    float4 w3 = *(const float4*)&W[(size_t)(k + 3) * FEATS + j0];
#pragma unroll
    for (int rr = 0; rr < 8; ++rr) {
      float4 h4 = *(const float4*)&hs[(ty * 8 + rr) * HPAD + k];
      acc[rr][0] += h4.x * w0.x + h4.y * w1.x + h4.z * w2.x + h4.w * w3.x;
      acc[rr][1] += h4.x * w0.y + h4.y * w1.y + h4.z * w2.y + h4.w * w3.y;
      acc[rr][2] += h4.x * w0.z + h4.y * w1.z + h4.z * w2.z + h4.w * w3.z;
      acc[rr][3] += h4.x * w0.w + h4.y * w1.w + h4.z * w2.w + h4.w * w3.w;
    }
  }

  float4 b4 = *(const float4*)&bias[j0];
#pragma unroll
  for (int rr = 0; rr < 8; ++rr) {
    int v = vbase + ty * 8 + rr;
    if (v < N) {
      float4 o;
      o.x = acc[rr][0] + b4.x;
      o.y = acc[rr][1] + b4.y;
      o.z = acc[rr][2] + b4.z;
      o.w = acc[rr][3] + b4.w;
      if (RELU) {
        o.x = fmaxf(o.x, 0.f);
        o.y = fmaxf(o.y, 0.f);
        o.z = fmaxf(o.z, 0.f);
        o.w = fmaxf(o.w, 0.f);
      }
      *(float4*)&out[(size_t)v * FEATS + j0] = o;
      if (WRITEH) {
        uint2 hu;
        hu.x = f2bf(o.x) | (f2bf(o.y) << 16);
        hu.y = f2bf(o.z) | (f2bf(o.w) << 16);
        *(uint2*)&Hh[(size_t)v * 64 + (j0 >> 1)] = hu;
      }
    }
  }
}

// ---------------- launcher ----------------

extern "C" void kernel_launch(void* const* d_in, const int* in_sizes, int n_in,
                              void* d_out, int out_size, void* d_ws, size_t ws_size,
                              hipStream_t stream) {
  const float* X = (const float*)d_in[0];
  const int* src = (const int*)d_in[1];
  const int* dst = (const int*)d_in[2];
  const float* W1 = (const float*)d_in[3];
  const float* b1 = (const float*)d_in[4];
  const float* W2 = (const float*)d_in[5];
  const float* b2 = (const float*)d_in[6];
  float* out = (float*)d_out;

  int N = in_sizes[0] / FEATS;
  int E = in_sizes[1];
  int nb = (N + SCAN_TILE - 1) / SCAN_TILE;
  int NB = (N + 255) / 256;  // dst-page buckets

  char* ws = (char*)d_ws;
  auto alloc = [&](size_t bytes) -> char* {
    char* p = ws;
    ws += (bytes + 255) & ~(size_t)255;
    return p;
  };
  int* deg = (int*)alloc((size_t)N * 4);
  int* off = (int*)alloc((size_t)N * 4);
  int* blockSums = (int*)alloc((size_t)nb * 4);
  int* blockOff = (int*)alloc((size_t)nb * 4);
  int* bucketCursor = (int*)alloc((size_t)NB_MAX * 4);
  uint2* pairs = (uint2*)alloc((size_t)E * 8);
  int* srcSorted = (int*)alloc((size_t)E * 4);
  uint32_t* Xh = (uint32_t*)alloc((size_t)N * 64 * 4);  // bf16 feature matrix (gather source)
  uint32_t* Ah = (uint32_t*)alloc((size_t)N * 64 * 4);  // bf16 aggregate

  // ---- CSR build ----
  hipMemsetAsync(deg, 0, (size_t)N * 4, stream);
  hist_kernel<<<(E + 255) / 256, 256, 0, stream>>>(dst, deg, E);
  scan1_kernel<<<nb, SCAN_B, 0, stream>>>(deg, off, blockSums, N);
  scan2_kernel<<<1, SCAN2_B, 0, stream>>>(blockSums, blockOff, nb);
  scan3_kernel<<<(N + 255) / 256, 256, 0, stream>>>(off, blockOff, N);
  initcur_kernel<<<1, NB_MAX, 0, stream>>>(off, bucketCursor, N, NB);
  pairscatter_kernel<<<(E + PS_CHUNK - 1) / PS_CHUNK, PS_B, 0, stream>>>(src, dst, bucketCursor,
                                                                         pairs, E);
  finalscatter_kernel<<<NB, 256, 0, stream>>>(pairs, off, srcSorted, N, E);

  // ---- bf16 copy of input features ----
  int ncast = N * 64;
  cast_kernel<<<(ncast + 255) / 256, 256, 0, stream>>>(X, Xh, ncast);

  int aggBlocks = (N + 3) / 4;
  int gb = (N + GM - 1) / GM;

  // ---- layer 1 ----
  agg_kernel<<<aggBlocks, 256, 0, stream>>>(Xh, srcSorted, off, deg, Ah, N);
  gemm_kernel<1, 1><<<gb, 256, 0, stream>>>(X, Ah, W1, b1, out, Xh, N);  // also emits bf16 h1 into Xh

  // ---- layer 2 ----
  agg_kernel<<<aggBlocks, 256, 0, stream>>>(Xh, srcSorted, off, deg, Ah, N);
  gemm_kernel<0, 0><<<gb, 256, 0, stream>>>(out, Ah, W2, b2, out, nullptr, N);
}

// Round 4
// 358.386 us; speedup vs baseline: 1.8224x; 1.0972x over previous
//
#include <hip/hip_runtime.h>
#include <hip/hip_bf16.h>
#include <stdint.h>

#define FEATS 128
#define SCAN_B 256
#define SCAN_ITEMS 4
#define SCAN_TILE (SCAN_B * SCAN_ITEMS)
#define SCAN2_B 1024
#define NB_MAX 512        // max buckets (supports N <= 131072)
#define PS_B 1024         // pair-scatter block threads
#define PS_EPT 16         // edges per thread
#define PS_CHUNK (PS_B * PS_EPT)
#define GP 136            // GEMM LDS pitch in shorts (272 B: 16B-aligned rows, 2-way max conflict)

typedef short bf16x8 __attribute__((ext_vector_type(8)));
typedef float f32x4 __attribute__((ext_vector_type(4)));

// ---------------- helpers ----------------

__device__ inline uint32_t f2bf(float f) {  // RTNE f32 -> bf16 (low 16 bits)
  uint32_t x = __float_as_uint(f);
  uint32_t r = ((x >> 16) & 1u) + 0x7fffu;
  return (x + r) >> 16;
}
__device__ inline float bflo(uint32_t u) { return __uint_as_float(u << 16); }
__device__ inline float bfhi(uint32_t u) { return __uint_as_float(u & 0xffff0000u); }

// ---------------- CSR build ----------------

__global__ void hist_kernel(const int* __restrict__ dst, int* __restrict__ deg, int E) {
  int i = blockIdx.x * blockDim.x + threadIdx.x;
  int stride = gridDim.x * blockDim.x;
  for (; i < E; i += stride) atomicAdd(&deg[dst[i]], 1);
}

__global__ void scan1_kernel(const int* __restrict__ deg, int* __restrict__ off,
                             int* __restrict__ blockSums, int N) {
  __shared__ int s[SCAN_B];
  int t = threadIdx.x;
  int base = blockIdx.x * SCAN_TILE + t * SCAN_ITEMS;
  int v[SCAN_ITEMS];
  int tsum = 0;
#pragma unroll
  for (int j = 0; j < SCAN_ITEMS; ++j) {
    int i = base + j;
    v[j] = (i < N) ? deg[i] : 0;
    tsum += v[j];
  }
  s[t] = tsum;
  __syncthreads();
  for (int o = 1; o < SCAN_B; o <<= 1) {
    int add = (t >= o) ? s[t - o] : 0;
    __syncthreads();
    s[t] += add;
    __syncthreads();
  }
  int run = s[t] - tsum;
#pragma unroll
  for (int j = 0; j < SCAN_ITEMS; ++j) {
    int i = base + j;
    if (i < N) off[i] = run;
    run += v[j];
  }
  if (t == SCAN_B - 1) blockSums[blockIdx.x] = run;
}

__global__ void scan2_kernel(const int* __restrict__ blockSums, int* __restrict__ blockOff, int nb) {
  __shared__ int s[SCAN2_B];
  int t = threadIdx.x;
  int v = (t < nb) ? blockSums[t] : 0;
  s[t] = v;
  __syncthreads();
  for (int o = 1; o < SCAN2_B; o <<= 1) {
    int add = (t >= o) ? s[t - o] : 0;
    __syncthreads();
    s[t] += add;
    __syncthreads();
  }
  if (t < nb) blockOff[t] = s[t] - v;
}

__global__ void scan3_kernel(int* __restrict__ off, const int* __restrict__ blockOff, int N) {
  int i = blockIdx.x * blockDim.x + threadIdx.x;
  int stride = gridDim.x * blockDim.x;
  for (; i < N; i += stride) off[i] = off[i] + blockOff[i / SCAN_TILE];
}

__global__ void initcur_kernel(const int* __restrict__ off, int* __restrict__ bucketCursor,
                               int N, int NB) {
  int b = threadIdx.x;
  if (b < NB) bucketCursor[b] = off[b * 256];
}

// ---- pass 2: multisplit packed (src<<8 | dst&255) into dst-page buckets ----
__global__ __launch_bounds__(PS_B) void pairscatter_kernel(const int* __restrict__ src,
                                                           const int* __restrict__ dst,
                                                           int* __restrict__ bucketCursor,
                                                           uint32_t* __restrict__ pairs, int E) {
  __shared__ int hist[NB_MAX];
  __shared__ int rank[NB_MAX];
  __shared__ int res[NB_MAX];
  int t = threadIdx.x;
  int base = blockIdx.x * PS_CHUNK;

  if (t < NB_MAX) {
    hist[t] = 0;
    rank[t] = 0;
  }
  __syncthreads();

  int sr[PS_EPT], dr[PS_EPT];
#pragma unroll
  for (int j = 0; j < PS_EPT; ++j) {
    int i = base + j * PS_B + t;
    if (i < E) {
      sr[j] = src[i];
      dr[j] = dst[i];
      atomicAdd(&hist[dr[j] >> 8], 1);
    } else {
      dr[j] = -1;
    }
  }
  __syncthreads();

  if (t < NB_MAX) {
    int h = hist[t];
    res[t] = h ? atomicAdd(&bucketCursor[t], h) : 0;
  }
  __syncthreads();

#pragma unroll
  for (int j = 0; j < PS_EPT; ++j) {
    if (dr[j] >= 0) {
      int b = dr[j] >> 8;
      int r = atomicAdd(&rank[b], 1);
      pairs[(size_t)(res[b] + r)] = ((uint32_t)sr[j] << 8) | ((uint32_t)dr[j] & 255u);
    }
  }
}

// ---- pass 3: within-bucket final scatter; node cursors in LDS ----
__global__ __launch_bounds__(256) void finalscatter_kernel(const uint32_t* __restrict__ pairs,
                                                           const int* __restrict__ off,
                                                           int* __restrict__ srcSorted,
                                                           int N, int E) {
  __shared__ int cur[256];
  int b = blockIdx.x;
  int t = threadIdx.x;
  int node = b * 256 + t;
  cur[t] = (node < N) ? off[node] : 0;
  __syncthreads();

  int bs = off[b * 256];
  int nxt = (b + 1) * 256;
  int be = (nxt < N) ? off[nxt] : E;
  for (int i = bs + t; i < be; i += 256) {
    uint32_t p = pairs[i];
    int pos = atomicAdd(&cur[p & 255u], 1);
    srcSorted[pos] = (int)(p >> 8);
  }
}

// ---------------- f32 -> bf16 cast of the whole feature matrix ----------------

__global__ void cast_kernel(const float* __restrict__ X, uint32_t* __restrict__ Xh, int n) {
  int i = blockIdx.x * blockDim.x + threadIdx.x;  // n = N*64 packed uints
  if (i >= n) return;
  float2 v = ((const float2*)X)[i];
  Xh[i] = f2bf(v.x) | (f2bf(v.y) << 16);
}

// ---------------- W [K=128][N=128] f32 -> Wt [n][k] bf16 packed u32 ----------------

__global__ void wtrans_kernel(const float* __restrict__ W, uint32_t* __restrict__ Wt) {
  __shared__ uint16_t s[128 * 129];
  int t = threadIdx.x;
  for (int i = t; i < 16384; i += 256) {
    int k = i >> 7, n = i & 127;
    s[n * 129 + k] = (uint16_t)f2bf(W[i]);
  }
  __syncthreads();
  for (int i = t; i < 8192; i += 256) {  // 8192 packed u32 outputs
    int n = i >> 6, kd = i & 63;
    uint32_t lo = s[n * 129 + kd * 2];
    uint32_t hi = s[n * 129 + kd * 2 + 1];
    Wt[i] = lo | (hi << 16);
  }
}

// ---------------- mean aggregation: one wave per node, bf16 gather, 8x unroll ----------------

__global__ void agg_kernel(const uint32_t* __restrict__ Xh, const int* __restrict__ srcSorted,
                           const int* __restrict__ off, const int* __restrict__ deg,
                           uint32_t* __restrict__ Ah, int N) {
  int wid = (int)((blockIdx.x * (unsigned)blockDim.x + threadIdx.x) >> 6);
  int lane = threadIdx.x & 63;
  if (wid >= N) return;
  int start = off[wid];
  int d = deg[wid];
  const uint32_t* Xl = Xh + lane;  // row stride = 64 uints (128 bf16)
  float a0 = 0.f, a1 = 0.f, b0 = 0.f, b1 = 0.f;
  float c0 = 0.f, c1 = 0.f, e0 = 0.f, e1 = 0.f;
  int i = 0;
  for (; i + 8 <= d; i += 8) {
    int s0 = srcSorted[start + i + 0];
    int s1 = srcSorted[start + i + 1];
    int s2 = srcSorted[start + i + 2];
    int s3 = srcSorted[start + i + 3];
    int s4 = srcSorted[start + i + 4];
    int s5 = srcSorted[start + i + 5];
    int s6 = srcSorted[start + i + 6];
    int s7 = srcSorted[start + i + 7];
    uint32_t u0 = Xl[(size_t)s0 << 6];
    uint32_t u1 = Xl[(size_t)s1 << 6];
    uint32_t u2 = Xl[(size_t)s2 << 6];
    uint32_t u3 = Xl[(size_t)s3 << 6];
    uint32_t u4 = Xl[(size_t)s4 << 6];
    uint32_t u5 = Xl[(size_t)s5 << 6];
    uint32_t u6 = Xl[(size_t)s6 << 6];
    uint32_t u7 = Xl[(size_t)s7 << 6];
    a0 += bflo(u0); a1 += bfhi(u0);
    b0 += bflo(u1); b1 += bfhi(u1);
    c0 += bflo(u2); c1 += bfhi(u2);
    e0 += bflo(u3); e1 += bfhi(u3);
    a0 += bflo(u4); a1 += bfhi(u4);
    b0 += bflo(u5); b1 += bfhi(u5);
    c0 += bflo(u6); c1 += bfhi(u6);
    e0 += bflo(u7); e1 += bfhi(u7);
  }
  for (; i < d; ++i) {
    int s = srcSorted[start + i];
    uint32_t u = Xl[(size_t)s << 6];
    a0 += bflo(u); a1 += bfhi(u);
  }
  float s0 = (a0 + b0) + (c0 + e0);
  float s1 = (a1 + b1) + (c1 + e1);
  float scale = (d > 0) ? (1.0f / (float)d) : 0.0f;
  Ah[(size_t)wid * 64 + lane] = f2bf(s0 * scale) | (f2bf(s1 * scale) << 16);
}

// ---------------- MFMA GEMM: out = (Xb + Ab) @ Wt^T + bias  (h staged bf16 in LDS) ----------------
// Xb/Ab: packed bf16 [N][64] u32.  Wt: [n][k] bf16 packed.  OUTF32: f32 d_out, else bf16 in-place.

template <int RELU, int OUTF32>
__global__ __launch_bounds__(256) void gemm_mfma(const uint32_t* __restrict__ Xb,
                                                 const uint32_t* __restrict__ Ab,
                                                 const uint32_t* __restrict__ Wt,
                                                 const float* __restrict__ bias,
                                                 float* __restrict__ outF,
                                                 uint32_t* __restrict__ outH, int N) {
  __shared__ short HS[64 * GP];
  __shared__ short WS[128 * GP];
  int t = threadIdx.x;
  int vbase = blockIdx.x * 64;

  // stage Wt (16B chunks): 2048 chunks of 8 shorts
  for (int c = t; c < 2048; c += 256) {
    int row = c >> 4, col8 = (c & 15) * 8;
    uint4 w = *(const uint4*)&Wt[row * 64 + (col8 >> 1)];
    *(uint4*)&WS[row * GP + col8] = w;
  }
  // stage h = Xb + Ab (bf16 sums), 4096 packed dwords
  for (int i = t; i < 4096; i += 256) {
    int row = i >> 6, c = i & 63;
    int v = vbase + row;
    uint32_t hv = 0;
    if (v < N) {
      uint32_t xu = Xb[(size_t)v * 64 + c];
      uint32_t au = Ab[(size_t)v * 64 + c];
      float lo = bflo(xu) + bflo(au);
      float hi = bfhi(xu) + bfhi(au);
      hv = f2bf(lo) | (f2bf(hi) << 16);
    }
    *(uint32_t*)&HS[row * GP + c * 2] = hv;
  }
  __syncthreads();

  int wave = t >> 6, l = t & 63;
  int wr = wave * 16;                    // wave's 16 output rows
  int lr = l & 15, lk = (l >> 4) * 8;    // fragment index / k offset

  f32x4 acc[8];
#pragma unroll
  for (int i = 0; i < 8; ++i) acc[i] = (f32x4){0.f, 0.f, 0.f, 0.f};

#pragma unroll
  for (int ks = 0; ks < 4; ++ks) {
    int k0 = ks * 32 + lk;
    bf16x8 a = *(const bf16x8*)&HS[(wr + lr) * GP + k0];
#pragma unroll
    for (int nf = 0; nf < 8; ++nf) {
      bf16x8 b = *(const bf16x8*)&WS[(nf * 16 + lr) * GP + k0];
      acc[nf] = __builtin_amdgcn_mfma_f32_16x16x32_bf16(a, b, acc[nf], 0, 0, 0);
    }
  }

  // epilogue: D col = lane&15, row = (lane>>4)*4 + j
  int orow = wr + (l >> 4) * 4;
#pragma unroll
  for (int nf = 0; nf < 8; ++nf) {
    int col = nf * 16 + lr;
    float bv = bias[col];
#pragma unroll
    for (int j = 0; j < 4; ++j) {
      int v = vbase + orow + j;
      if (v < N) {
        float o = acc[nf][j] + bv;
        if (RELU) o = fmaxf(o, 0.f);
        if (OUTF32) {
          outF[(size_t)v * FEATS + col] = o;
        } else {
          ((uint16_t*)outH)[(size_t)v * FEATS + col] = (uint16_t)f2bf(o);
        }
      }
    }
  }
}

// ---------------- launcher ----------------

extern "C" void kernel_launch(void* const* d_in, const int* in_sizes, int n_in,
                              void* d_out, int out_size, void* d_ws, size_t ws_size,
                              hipStream_t stream) {
  const float* X = (const float*)d_in[0];
  const int* src = (const int*)d_in[1];
  const int* dst = (const int*)d_in[2];
  const float* W1 = (const float*)d_in[3];
  const float* b1 = (const float*)d_in[4];
  const float* W2 = (const float*)d_in[5];
  const float* b2 = (const float*)d_in[6];
  float* out = (float*)d_out;

  int N = in_sizes[0] / FEATS;
  int E = in_sizes[1];
  int nb = (N + SCAN_TILE - 1) / SCAN_TILE;
  int NB = (N + 255) / 256;  // dst-page buckets

  char* ws = (char*)d_ws;
  auto alloc = [&](size_t bytes) -> char* {
    char* p = ws;
    ws += (bytes + 255) & ~(size_t)255;
    return p;
  };
  int* deg = (int*)alloc((size_t)N * 4);
  int* off = (int*)alloc((size_t)N * 4);
  int* blockSums = (int*)alloc((size_t)nb * 4);
  int* blockOff = (int*)alloc((size_t)nb * 4);
  int* bucketCursor = (int*)alloc((size_t)NB_MAX * 4);
  uint32_t* pairs = (uint32_t*)alloc((size_t)E * 4);
  int* srcSorted = (int*)alloc((size_t)E * 4);
  uint32_t* Xh = (uint32_t*)alloc((size_t)N * 64 * 4);  // bf16 features; becomes bf16 h1 after gemm1
  uint32_t* Ah = (uint32_t*)alloc((size_t)N * 64 * 4);  // bf16 aggregate
  uint32_t* Wt1 = (uint32_t*)alloc((size_t)64 * 128 * 4);
  uint32_t* Wt2 = (uint32_t*)alloc((size_t)64 * 128 * 4);

  // ---- CSR build ----
  hipMemsetAsync(deg, 0, (size_t)N * 4, stream);
  hist_kernel<<<(E + 255) / 256, 256, 0, stream>>>(dst, deg, E);
  scan1_kernel<<<nb, SCAN_B, 0, stream>>>(deg, off, blockSums, N);
  scan2_kernel<<<1, SCAN2_B, 0, stream>>>(blockSums, blockOff, nb);
  scan3_kernel<<<(N + 255) / 256, 256, 0, stream>>>(off, blockOff, N);
  initcur_kernel<<<1, NB_MAX, 0, stream>>>(off, bucketCursor, N, NB);
  pairscatter_kernel<<<(E + PS_CHUNK - 1) / PS_CHUNK, PS_B, 0, stream>>>(src, dst, bucketCursor,
                                                                         pairs, E);
  finalscatter_kernel<<<NB, 256, 0, stream>>>(pairs, off, srcSorted, N, E);

  // ---- casts ----
  int ncast = N * 64;
  cast_kernel<<<(ncast + 255) / 256, 256, 0, stream>>>(X, Xh, ncast);
  wtrans_kernel<<<1, 256, 0, stream>>>(W1, Wt1);
  wtrans_kernel<<<1, 256, 0, stream>>>(W2, Wt2);

  int aggBlocks = (N + 3) / 4;
  int gb = (N + 63) / 64;

  // ---- layer 1: Ah = agg(Xh); Xh <- bf16(relu((Xh+Ah)@W1+b1))  (in-place) ----
  agg_kernel<<<aggBlocks, 256, 0, stream>>>(Xh, srcSorted, off, deg, Ah, N);
  gemm_mfma<1, 0><<<gb, 256, 0, stream>>>(Xh, Ah, Wt1, b1, nullptr, Xh, N);

  // ---- layer 2: Ah = agg(h1); out = (h1+Ah)@W2+b2  (f32) ----
  agg_kernel<<<aggBlocks, 256, 0, stream>>>(Xh, srcSorted, off, deg, Ah, N);
  gemm_mfma<0, 1><<<gb, 256, 0, stream>>>(Xh, Ah, Wt2, b2, out, nullptr, N);
}

// Round 5
// 326.094 us; speedup vs baseline: 2.0028x; 1.0990x over previous
//
#include <hip/hip_runtime.h>
#include <hip/hip_bf16.h>
#include <stdint.h>

#define FEATS 128
#define SCAN_B 256
#define SCAN_ITEMS 4
#define SCAN_TILE (SCAN_B * SCAN_ITEMS)
#define SCAN2_B 1024
#define NB_MAX 512        // max buckets (supports N <= 131072)
#define PS_B 1024         // pair-scatter block threads
#define PS_EPT 16         // edges per thread
#define PS_CHUNK (PS_B * PS_EPT)
#define GP 136            // GEMM LDS pitch in shorts (272 B rows: 16B-aligned, 2-way max conflict)

typedef short bf16x8 __attribute__((ext_vector_type(8)));
typedef float f32x4 __attribute__((ext_vector_type(4)));
typedef float f32x2 __attribute__((ext_vector_type(2)));

// ---------------- helpers ----------------

__device__ inline uint32_t f2bf(float f) {  // RTNE f32 -> bf16 (low 16 bits)
  uint32_t x = __float_as_uint(f);
  uint32_t r = ((x >> 16) & 1u) + 0x7fffu;
  return (x + r) >> 16;
}
__device__ inline float bflo(uint32_t u) { return __uint_as_float(u << 16); }
__device__ inline float bfhi(uint32_t u) { return __uint_as_float(u & 0xffff0000u); }

// ---------------- prep: f32->fp8 cast of X  +  dst-degree histogram ----------------

__global__ void prep_kernel(const float* __restrict__ X, uint32_t* __restrict__ Xq, int nq,
                            const int* __restrict__ dst, int* __restrict__ deg, int E) {
  int tid = blockIdx.x * blockDim.x + threadIdx.x;
  int stride = gridDim.x * blockDim.x;
  for (int i = tid; i < nq; i += stride) {  // nq = N*32 (4 feats per u32)
    float4 v = ((const float4*)X)[i];
    uint32_t q = __builtin_amdgcn_cvt_pk_fp8_f32(v.x, v.y, 0, false);
    q = __builtin_amdgcn_cvt_pk_fp8_f32(v.z, v.w, q, true);
    Xq[i] = q;
  }
  for (int i = tid; i < E; i += stride) atomicAdd(&deg[dst[i]], 1);
}

// ---------------- CSR build ----------------

__global__ void scan1_kernel(const int* __restrict__ deg, int* __restrict__ off,
                             int* __restrict__ blockSums, int N) {
  __shared__ int s[SCAN_B];
  int t = threadIdx.x;
  int base = blockIdx.x * SCAN_TILE + t * SCAN_ITEMS;
  int v[SCAN_ITEMS];
  int tsum = 0;
#pragma unroll
  for (int j = 0; j < SCAN_ITEMS; ++j) {
    int i = base + j;
    v[j] = (i < N) ? deg[i] : 0;
    tsum += v[j];
  }
  s[t] = tsum;
  __syncthreads();
  for (int o = 1; o < SCAN_B; o <<= 1) {
    int add = (t >= o) ? s[t - o] : 0;
    __syncthreads();
    s[t] += add;
    __syncthreads();
  }
  int run = s[t] - tsum;
#pragma unroll
  for (int j = 0; j < SCAN_ITEMS; ++j) {
    int i = base + j;
    if (i < N) off[i] = run;
    run += v[j];
  }
  if (t == SCAN_B - 1) blockSums[blockIdx.x] = run;
}

__global__ void scan2_kernel(const int* __restrict__ blockSums, int* __restrict__ blockOff, int nb) {
  __shared__ int s[SCAN2_B];
  int t = threadIdx.x;
  int v = (t < nb) ? blockSums[t] : 0;
  s[t] = v;
  __syncthreads();
  for (int o = 1; o < SCAN2_B; o <<= 1) {
    int add = (t >= o) ? s[t - o] : 0;
    __syncthreads();
    s[t] += add;
    __syncthreads();
  }
  if (t < nb) blockOff[t] = s[t] - v;
}

__global__ void scan3_kernel(int* __restrict__ off, const int* __restrict__ blockOff,
                             int* __restrict__ bucketCursor, int N) {
  int i = blockIdx.x * blockDim.x + threadIdx.x;
  int stride = gridDim.x * blockDim.x;
  for (; i < N; i += stride) {
    int o = off[i] + blockOff[i / SCAN_TILE];
    off[i] = o;
    if ((i & 255) == 0) bucketCursor[i >> 8] = o;
  }
}

// ---- pass 2: multisplit packed (src<<8 | dst&255) into dst-page buckets ----
__global__ __launch_bounds__(PS_B) void pairscatter_kernel(const int* __restrict__ src,
                                                           const int* __restrict__ dst,
                                                           int* __restrict__ bucketCursor,
                                                           uint32_t* __restrict__ pairs, int E) {
  __shared__ int hist[NB_MAX];
  __shared__ int rank[NB_MAX];
  __shared__ int res[NB_MAX];
  int t = threadIdx.x;
  int base = blockIdx.x * PS_CHUNK;

  if (t < NB_MAX) {
    hist[t] = 0;
    rank[t] = 0;
  }
  __syncthreads();

  int sr[PS_EPT], dr[PS_EPT];
#pragma unroll
  for (int j = 0; j < PS_EPT; ++j) {
    int i = base + j * PS_B + t;
    if (i < E) {
      sr[j] = src[i];
      dr[j] = dst[i];
      atomicAdd(&hist[dr[j] >> 8], 1);
    } else {
      dr[j] = -1;
    }
  }
  __syncthreads();

  if (t < NB_MAX) {
    int h = hist[t];
    res[t] = h ? atomicAdd(&bucketCursor[t], h) : 0;
  }
  __syncthreads();

#pragma unroll
  for (int j = 0; j < PS_EPT; ++j) {
    if (dr[j] >= 0) {
      int b = dr[j] >> 8;
      int r = atomicAdd(&rank[b], 1);
      pairs[(size_t)(res[b] + r)] = ((uint32_t)sr[j] << 8) | ((uint32_t)dr[j] & 255u);
    }
  }
}

// ---- pass 3: within-bucket final scatter; node cursors in LDS ----
__global__ __launch_bounds__(256) void finalscatter_kernel(const uint32_t* __restrict__ pairs,
                                                           const int* __restrict__ off,
                                                           int* __restrict__ srcSorted,
                                                           int N, int E) {
  __shared__ int cur[256];
  int b = blockIdx.x;
  int t = threadIdx.x;
  int node = b * 256 + t;
  cur[t] = (node < N) ? off[node] : 0;
  __syncthreads();

  int bs = off[b * 256];
  int nxt = (b + 1) * 256;
  int be = (nxt < N) ? off[nxt] : E;
  for (int i = bs + t; i < be; i += 256) {
    uint32_t p = pairs[i];
    int pos = atomicAdd(&cur[p & 255u], 1);
    srcSorted[pos] = (int)(p >> 8);
  }
}

// ---------------- W [K=128][N=128] f32 -> Wt [n][k] bf16 packed (2 matrices, 2 blocks) ----------------

__global__ void wtrans_kernel(const float* __restrict__ W1, const float* __restrict__ W2,
                              uint32_t* __restrict__ Wt1, uint32_t* __restrict__ Wt2) {
  __shared__ uint16_t s[128 * 129];
  const float* W = blockIdx.x ? W2 : W1;
  uint32_t* Wt = blockIdx.x ? Wt2 : Wt1;
  int t = threadIdx.x;
  for (int i = t; i < 16384; i += 256) {
    int k = i >> 7, n = i & 127;
    s[n * 129 + k] = (uint16_t)f2bf(W[i]);
  }
  __syncthreads();
  for (int i = t; i < 8192; i += 256) {
    int n = i >> 6, kd = i & 63;
    uint32_t lo = s[n * 129 + kd * 2];
    uint32_t hi = s[n * 129 + kd * 2 + 1];
    Wt[i] = lo | (hi << 16);
  }
}

// ---------------- mean aggregation: one wave per node, fp8 gather (128 B/row), 8x unroll ----------------

__global__ void agg_kernel(const uint16_t* __restrict__ Xq, const int* __restrict__ srcSorted,
                           const int* __restrict__ off, const int* __restrict__ deg,
                           uint32_t* __restrict__ Ah, int N) {
  int wid = (int)((blockIdx.x * (unsigned)blockDim.x + threadIdx.x) >> 6);
  int lane = threadIdx.x & 63;
  if (wid >= N) return;
  int start = off[wid];
  int d = deg[wid];
  const uint16_t* Xl = Xq + lane;  // row stride = 64 u16 (128 fp8); lane holds feats 2l,2l+1
  float a0 = 0.f, a1 = 0.f, b0 = 0.f, b1 = 0.f;
  float c0 = 0.f, c1 = 0.f, e0 = 0.f, e1 = 0.f;
  int i = 0;
  for (; i + 8 <= d; i += 8) {
    int s0 = srcSorted[start + i + 0];
    int s1 = srcSorted[start + i + 1];
    int s2 = srcSorted[start + i + 2];
    int s3 = srcSorted[start + i + 3];
    int s4 = srcSorted[start + i + 4];
    int s5 = srcSorted[start + i + 5];
    int s6 = srcSorted[start + i + 6];
    int s7 = srcSorted[start + i + 7];
    uint32_t u0 = Xl[(size_t)s0 << 6];
    uint32_t u1 = Xl[(size_t)s1 << 6];
    uint32_t u2 = Xl[(size_t)s2 << 6];
    uint32_t u3 = Xl[(size_t)s3 << 6];
    uint32_t u4 = Xl[(size_t)s4 << 6];
    uint32_t u5 = Xl[(size_t)s5 << 6];
    uint32_t u6 = Xl[(size_t)s6 << 6];
    uint32_t u7 = Xl[(size_t)s7 << 6];
    f32x2 v0 = __builtin_amdgcn_cvt_pk_f32_fp8(u0, false);
    f32x2 v1 = __builtin_amdgcn_cvt_pk_f32_fp8(u1, false);
    f32x2 v2 = __builtin_amdgcn_cvt_pk_f32_fp8(u2, false);
    f32x2 v3 = __builtin_amdgcn_cvt_pk_f32_fp8(u3, false);
    f32x2 v4 = __builtin_amdgcn_cvt_pk_f32_fp8(u4, false);
    f32x2 v5 = __builtin_amdgcn_cvt_pk_f32_fp8(u5, false);
    f32x2 v6 = __builtin_amdgcn_cvt_pk_f32_fp8(u6, false);
    f32x2 v7 = __builtin_amdgcn_cvt_pk_f32_fp8(u7, false);
    a0 += v0.x; a1 += v0.y;
    b0 += v1.x; b1 += v1.y;
    c0 += v2.x; c1 += v2.y;
    e0 += v3.x; e1 += v3.y;
    a0 += v4.x; a1 += v4.y;
    b0 += v5.x; b1 += v5.y;
    c0 += v6.x; c1 += v6.y;
    e0 += v7.x; e1 += v7.y;
  }
  for (; i < d; ++i) {
    int s = srcSorted[start + i];
    uint32_t u = Xl[(size_t)s << 6];
    f32x2 v = __builtin_amdgcn_cvt_pk_f32_fp8(u, false);
    a0 += v.x; a1 += v.y;
  }
  float s0 = (a0 + b0) + (c0 + e0);
  float s1 = (a1 + b1) + (c1 + e1);
  float scale = (d > 0) ? (1.0f / (float)d) : 0.0f;
  Ah[(size_t)wid * 64 + lane] = f2bf(s0 * scale) | (f2bf(s1 * scale) << 16);
}

// ---------------- MFMA GEMM: out = (x + A) @ Wt^T + bias ----------------
// LAYER=1: x from f32 X; writes bf16 h1 (outH) + fp8 h1 (outQ), RELU.
// LAYER=2: x from bf16 Hh; writes f32 d_out.

template <int LAYER>
__global__ __launch_bounds__(256) void gemm_mfma(const float* __restrict__ Xf,
                                                 const uint32_t* __restrict__ Xb,
                                                 const uint32_t* __restrict__ Ab,
                                                 const uint32_t* __restrict__ Wt,
                                                 const float* __restrict__ bias,
                                                 float* __restrict__ outF,
                                                 uint32_t* __restrict__ outH,
                                                 uint8_t* __restrict__ outQ, int N) {
  __shared__ short HS[64 * GP];
  __shared__ short WS[128 * GP];
  int t = threadIdx.x;
  int vbase = blockIdx.x * 64;

  // stage Wt (16B chunks): 2048 chunks of 8 shorts
  for (int c = t; c < 2048; c += 256) {
    int row = c >> 4, col8 = (c & 15) * 8;
    uint4 w = *(const uint4*)&Wt[row * 64 + (col8 >> 1)];
    *(uint4*)&WS[row * GP + col8] = w;
  }
  // stage h = x + A as bf16
  if (LAYER == 1) {
    for (int i = t; i < 2048; i += 256) {  // 64 rows x 32 float4
      int row = i >> 5, c4 = (i & 31) * 4;
      int v = vbase + row;
      uint2 hv = make_uint2(0, 0);
      if (v < N) {
        float4 xv = *(const float4*)&Xf[(size_t)v * FEATS + c4];
        uint2 au = *(const uint2*)&Ab[(size_t)v * 64 + (c4 >> 1)];
        hv.x = f2bf(xv.x + bflo(au.x)) | (f2bf(xv.y + bfhi(au.x)) << 16);
        hv.y = f2bf(xv.z + bflo(au.y)) | (f2bf(xv.w + bfhi(au.y)) << 16);
      }
      *(uint2*)&HS[row * GP + c4] = hv;
    }
  } else {
    for (int i = t; i < 4096; i += 256) {  // 64 rows x 64 dwords
      int row = i >> 6, c = i & 63;
      int v = vbase + row;
      uint32_t hv = 0;
      if (v < N) {
        uint32_t xu = Xb[(size_t)v * 64 + c];
        uint32_t au = Ab[(size_t)v * 64 + c];
        hv = f2bf(bflo(xu) + bflo(au)) | (f2bf(bfhi(xu) + bfhi(au)) << 16);
      }
      *(uint32_t*)&HS[row * GP + c * 2] = hv;
    }
  }
  __syncthreads();

  int wave = t >> 6, l = t & 63;
  int wr = wave * 16;                    // wave's 16 output rows
  int lr = l & 15, lk = (l >> 4) * 8;    // fragment index / k offset

  f32x4 acc[8];
#pragma unroll
  for (int i = 0; i < 8; ++i) acc[i] = (f32x4){0.f, 0.f, 0.f, 0.f};

#pragma unroll
  for (int ks = 0; ks < 4; ++ks) {
    int k0 = ks * 32 + lk;
    bf16x8 a = *(const bf16x8*)&HS[(wr + lr) * GP + k0];
#pragma unroll
    for (int nf = 0; nf < 8; ++nf) {
      bf16x8 b = *(const bf16x8*)&WS[(nf * 16 + lr) * GP + k0];
      acc[nf] = __builtin_amdgcn_mfma_f32_16x16x32_bf16(a, b, acc[nf], 0, 0, 0);
    }
  }

  // epilogue: D col = lane&15, row = (lane>>4)*4 + j
  int orow = wr + (l >> 4) * 4;
#pragma unroll
  for (int nf = 0; nf < 8; ++nf) {
    int col = nf * 16 + lr;
    float bv = bias[col];
#pragma unroll
    for (int j = 0; j < 4; ++j) {
      int v = vbase + orow + j;
      if (v < N) {
        float o = acc[nf][j] + bv;
        if (LAYER == 1) {
          o = fmaxf(o, 0.f);
          ((uint16_t*)outH)[(size_t)v * FEATS + col] = (uint16_t)f2bf(o);
          outQ[(size_t)v * FEATS + col] =
              (uint8_t)(__builtin_amdgcn_cvt_pk_fp8_f32(o, o, 0, false) & 0xffu);
        } else {
          outF[(size_t)v * FEATS + col] = o;
        }
      }
    }
  }
}

// ---------------- launcher ----------------

extern "C" void kernel_launch(void* const* d_in, const int* in_sizes, int n_in,
                              void* d_out, int out_size, void* d_ws, size_t ws_size,
                              hipStream_t stream) {
  const float* X = (const float*)d_in[0];
  const int* src = (const int*)d_in[1];
  const int* dst = (const int*)d_in[2];
  const float* W1 = (const float*)d_in[3];
  const float* b1 = (const float*)d_in[4];
  const float* W2 = (const float*)d_in[5];
  const float* b2 = (const float*)d_in[6];
  float* out = (float*)d_out;

  int N = in_sizes[0] / FEATS;
  int E = in_sizes[1];
  int nb = (N + SCAN_TILE - 1) / SCAN_TILE;
  int NB = (N + 255) / 256;  // dst-page buckets

  char* ws = (char*)d_ws;
  auto alloc = [&](size_t bytes) -> char* {
    char* p = ws;
    ws += (bytes + 255) & ~(size_t)255;
    return p;
  };
  int* deg = (int*)alloc((size_t)N * 4);
  int* off = (int*)alloc((size_t)N * 4);
  int* blockSums = (int*)alloc((size_t)nb * 4);
  int* blockOff = (int*)alloc((size_t)nb * 4);
  int* bucketCursor = (int*)alloc((size_t)NB_MAX * 4);
  uint32_t* pairs = (uint32_t*)alloc((size_t)E * 4);
  int* srcSorted = (int*)alloc((size_t)E * 4);
  uint32_t* Xq = (uint32_t*)alloc((size_t)N * 32 * 4);  // fp8 X; becomes fp8 h1 after gemm1 (alias)
  uint32_t* Ah = (uint32_t*)alloc((size_t)N * 64 * 4);  // bf16 aggregate
  uint32_t* Hh = (uint32_t*)alloc((size_t)N * 64 * 4);  // bf16 h1
  uint32_t* Wt1 = (uint32_t*)alloc((size_t)64 * 128 * 4);
  uint32_t* Wt2 = (uint32_t*)alloc((size_t)64 * 128 * 4);
  uint32_t* Hq = Xq;  // safe alias: Xq fully consumed by agg1 before gemm1 writes Hq

  // ---- prep: fp8 cast + degree histogram ----
  hipMemsetAsync(deg, 0, (size_t)N * 4, stream);
  int nq = N * 32;
  prep_kernel<<<(nq + 255) / 256, 256, 0, stream>>>(X, Xq, nq, dst, deg, E);

  // ---- CSR build ----
  scan1_kernel<<<nb, SCAN_B, 0, stream>>>(deg, off, blockSums, N);
  scan2_kernel<<<1, SCAN2_B, 0, stream>>>(blockSums, blockOff, nb);
  scan3_kernel<<<(N + 255) / 256, 256, 0, stream>>>(off, blockOff, bucketCursor, N);
  pairscatter_kernel<<<(E + PS_CHUNK - 1) / PS_CHUNK, PS_B, 0, stream>>>(src, dst, bucketCursor,
                                                                         pairs, E);
  finalscatter_kernel<<<NB, 256, 0, stream>>>(pairs, off, srcSorted, N, E);

  // ---- weights ----
  wtrans_kernel<<<2, 256, 0, stream>>>(W1, W2, Wt1, Wt2);

  int aggBlocks = (N + 3) / 4;
  int gb = (N + 63) / 64;

  // ---- layer 1: Ah = agg_fp8(Xq); Hh/Hq = relu((X+Ah)@W1+b1) ----
  agg_kernel<<<aggBlocks, 256, 0, stream>>>((const uint16_t*)Xq, srcSorted, off, deg, Ah, N);
  gemm_mfma<1><<<gb, 256, 0, stream>>>(X, nullptr, Ah, Wt1, b1, nullptr, Hh, (uint8_t*)Hq, N);

  // ---- layer 2: Ah = agg_fp8(Hq); out = (Hh+Ah)@W2+b2 (f32) ----
  agg_kernel<<<aggBlocks, 256, 0, stream>>>((const uint16_t*)Hq, srcSorted, off, deg, Ah, N);
  gemm_mfma<2><<<gb, 256, 0, stream>>>(nullptr, Hh, Ah, Wt2, b2, out, nullptr, nullptr, N);
}

// Round 6
// 276.425 us; speedup vs baseline: 2.3627x; 1.1797x over previous
//
#include <hip/hip_runtime.h>
#include <hip/hip_bf16.h>
#include <stdint.h>

#define FEATS 128
#define NB_MAX 512        // max buckets (supports N <= 131072)
#define PS_B 1024         // pair-scatter block threads
#define PS_EPT 16         // edges per thread
#define PS_CHUNK (PS_B * PS_EPT)
#define GP 136            // GEMM LDS pitch in shorts (272 B rows: 16B-aligned, 2-way max conflict)

typedef short bf16x8 __attribute__((ext_vector_type(8)));
typedef float f32x4 __attribute__((ext_vector_type(4)));
typedef float f32x2 __attribute__((ext_vector_type(2)));

// ---------------- helpers ----------------

__device__ inline uint32_t f2bf(float f) {  // RTNE f32 -> bf16 (low 16 bits)
  uint32_t x = __float_as_uint(f);
  uint32_t r = ((x >> 16) & 1u) + 0x7fffu;
  return (x + r) >> 16;
}
__device__ inline float bflo(uint32_t u) { return __uint_as_float(u << 16); }
__device__ inline float bfhi(uint32_t u) { return __uint_as_float(u & 0xffff0000u); }

// ---------------- cast: f32 -> fp8 e4m3 of X (pure streaming) ----------------

__global__ void cast_kernel(const float* __restrict__ X, uint32_t* __restrict__ Xq, int nq) {
  int i = blockIdx.x * blockDim.x + threadIdx.x;
  int stride = gridDim.x * blockDim.x;
  for (; i < nq; i += stride) {  // nq = N*32 (4 feats per u32)
    float4 v = ((const float4*)X)[i];
    uint32_t q = __builtin_amdgcn_cvt_pk_fp8_f32(v.x, v.y, 0, false);
    q = __builtin_amdgcn_cvt_pk_fp8_f32(v.z, v.w, q, true);
    Xq[i] = q;
  }
}

// ---------------- bucket histogram: LDS 512-bin, 1 global atomic per (block,bin) ----------------

__global__ void bucket_hist_kernel(const int* __restrict__ dst, int* __restrict__ bucketTotal,
                                   int E, int NB) {
  __shared__ int lh[NB_MAX];
  int t = threadIdx.x;
  for (int i = t; i < NB_MAX; i += 256) lh[i] = 0;
  __syncthreads();
  int i = blockIdx.x * blockDim.x + t;
  int stride = gridDim.x * blockDim.x;
  for (; i < E; i += stride) atomicAdd(&lh[dst[i] >> 8], 1);
  __syncthreads();
  for (int b = t; b < NB; b += 256) {
    int v = lh[b];
    if (v) atomicAdd(&bucketTotal[b], v);
  }
}

// ---------------- bucket scan: exclusive scan of bucket totals ----------------

__global__ void bucket_scan_kernel(const int* __restrict__ bucketTotal, int* __restrict__ bucketBase,
                                   int* __restrict__ bucketCursor, int NB) {
  __shared__ int s[NB_MAX];
  int t = threadIdx.x;
  int v = (t < NB) ? bucketTotal[t] : 0;
  s[t] = v;
  __syncthreads();
  for (int o = 1; o < NB_MAX; o <<= 1) {
    int add = (t >= o) ? s[t - o] : 0;
    __syncthreads();
    s[t] += add;
    __syncthreads();
  }
  if (t < NB) {
    int ex = s[t] - v;
    bucketBase[t] = ex;
    bucketCursor[t] = ex;
    if (t == NB - 1) bucketBase[NB] = s[t];  // = E
  }
}

// ---- pass 2: multisplit packed (src<<8 | dst&255) into dst-page buckets ----
__global__ __launch_bounds__(PS_B) void pairscatter_kernel(const int* __restrict__ src,
                                                           const int* __restrict__ dst,
                                                           int* __restrict__ bucketCursor,
                                                           uint32_t* __restrict__ pairs, int E) {
  __shared__ int hist[NB_MAX];
  __shared__ int rank[NB_MAX];
  __shared__ int res[NB_MAX];
  int t = threadIdx.x;
  int base = blockIdx.x * PS_CHUNK;

  if (t < NB_MAX) {
    hist[t] = 0;
    rank[t] = 0;
  }
  __syncthreads();

  int sr[PS_EPT], dr[PS_EPT];
#pragma unroll
  for (int j = 0; j < PS_EPT; ++j) {
    int i = base + j * PS_B + t;
    if (i < E) {
      sr[j] = src[i];
      dr[j] = dst[i];
      atomicAdd(&hist[dr[j] >> 8], 1);
    } else {
      dr[j] = -1;
    }
  }
  __syncthreads();

  if (t < NB_MAX) {
    int h = hist[t];
    res[t] = h ? atomicAdd(&bucketCursor[t], h) : 0;
  }
  __syncthreads();

#pragma unroll
  for (int j = 0; j < PS_EPT; ++j) {
    if (dr[j] >= 0) {
      int b = dr[j] >> 8;
      int r = atomicAdd(&rank[b], 1);
      pairs[(size_t)(res[b] + r)] = ((uint32_t)sr[j] << 8) | ((uint32_t)dr[j] & 255u);
    }
  }
}

// ---- fused final: per-bucket degree count (LDS) + scan (LDS) + deg/off write + scatter ----
__global__ __launch_bounds__(256) void fused_final_kernel(const uint32_t* __restrict__ pairs,
                                                          const int* __restrict__ bucketBase,
                                                          int* __restrict__ deg,
                                                          int* __restrict__ off,
                                                          int* __restrict__ srcSorted, int N) {
  __shared__ int cnt[256];
  __shared__ int scn[256];
  __shared__ int cur[256];
  int b = blockIdx.x, t = threadIdx.x;
  int bs = bucketBase[b], be = bucketBase[b + 1];
  cnt[t] = 0;
  __syncthreads();
  for (int i = bs + t; i < be; i += 256) atomicAdd(&cnt[pairs[i] & 255u], 1);
  __syncthreads();
  int v = cnt[t];
  scn[t] = v;
  __syncthreads();
  for (int o = 1; o < 256; o <<= 1) {
    int add = (t >= o) ? scn[t - o] : 0;
    __syncthreads();
    scn[t] += add;
    __syncthreads();
  }
  int myoff = bs + scn[t] - v;
  int node = b * 256 + t;
  if (node < N) {
    deg[node] = v;
    off[node] = myoff;
  }
  cur[t] = myoff;
  __syncthreads();
  for (int i = bs + t; i < be; i += 256) {
    uint32_t p = pairs[i];
    int pos = atomicAdd(&cur[p & 255u], 1);
    srcSorted[pos] = (int)(p >> 8);
  }
}

// ---------------- W [K=128][N=128] f32 -> Wt [n][k] bf16 packed (2 matrices, 2 blocks) ----------------

__global__ void wtrans_kernel(const float* __restrict__ W1, const float* __restrict__ W2,
                              uint32_t* __restrict__ Wt1, uint32_t* __restrict__ Wt2) {
  __shared__ uint16_t s[128 * 129];
  const float* W = blockIdx.x ? W2 : W1;
  uint32_t* Wt = blockIdx.x ? Wt2 : Wt1;
  int t = threadIdx.x;
  for (int i = t; i < 16384; i += 256) {
    int k = i >> 7, n = i & 127;
    s[n * 129 + k] = (uint16_t)f2bf(W[i]);
  }
  __syncthreads();
  for (int i = t; i < 8192; i += 256) {
    int n = i >> 6, kd = i & 63;
    uint32_t lo = s[n * 129 + kd * 2];
    uint32_t hi = s[n * 129 + kd * 2 + 1];
    Wt[i] = lo | (hi << 16);
  }
}

// ---------------- mean aggregation: one wave per node, fp8 gather (128 B/row), 8x unroll ----------------

__global__ void agg_kernel(const uint16_t* __restrict__ Xq, const int* __restrict__ srcSorted,
                           const int* __restrict__ off, const int* __restrict__ deg,
                           uint32_t* __restrict__ Ah, int N) {
  int wid = (int)((blockIdx.x * (unsigned)blockDim.x + threadIdx.x) >> 6);
  int lane = threadIdx.x & 63;
  if (wid >= N) return;
  int start = off[wid];
  int d = deg[wid];
  const uint16_t* Xl = Xq + lane;  // row stride = 64 u16 (128 fp8); lane holds feats 2l,2l+1
  float a0 = 0.f, a1 = 0.f, b0 = 0.f, b1 = 0.f;
  float c0 = 0.f, c1 = 0.f, e0 = 0.f, e1 = 0.f;
  int i = 0;
  for (; i + 8 <= d; i += 8) {
    int s0 = srcSorted[start + i + 0];
    int s1 = srcSorted[start + i + 1];
    int s2 = srcSorted[start + i + 2];
    int s3 = srcSorted[start + i + 3];
    int s4 = srcSorted[start + i + 4];
    int s5 = srcSorted[start + i + 5];
    int s6 = srcSorted[start + i + 6];
    int s7 = srcSorted[start + i + 7];
    uint32_t u0 = Xl[(size_t)s0 << 6];
    uint32_t u1 = Xl[(size_t)s1 << 6];
    uint32_t u2 = Xl[(size_t)s2 << 6];
    uint32_t u3 = Xl[(size_t)s3 << 6];
    uint32_t u4 = Xl[(size_t)s4 << 6];
    uint32_t u5 = Xl[(size_t)s5 << 6];
    uint32_t u6 = Xl[(size_t)s6 << 6];
    uint32_t u7 = Xl[(size_t)s7 << 6];
    f32x2 v0 = __builtin_amdgcn_cvt_pk_f32_fp8(u0, false);
    f32x2 v1 = __builtin_amdgcn_cvt_pk_f32_fp8(u1, false);
    f32x2 v2 = __builtin_amdgcn_cvt_pk_f32_fp8(u2, false);
    f32x2 v3 = __builtin_amdgcn_cvt_pk_f32_fp8(u3, false);
    f32x2 v4 = __builtin_amdgcn_cvt_pk_f32_fp8(u4, false);
    f32x2 v5 = __builtin_amdgcn_cvt_pk_f32_fp8(u5, false);
    f32x2 v6 = __builtin_amdgcn_cvt_pk_f32_fp8(u6, false);
    f32x2 v7 = __builtin_amdgcn_cvt_pk_f32_fp8(u7, false);
    a0 += v0.x; a1 += v0.y;
    b0 += v1.x; b1 += v1.y;
    c0 += v2.x; c1 += v2.y;
    e0 += v3.x; e1 += v3.y;
    a0 += v4.x; a1 += v4.y;
    b0 += v5.x; b1 += v5.y;
    c0 += v6.x; c1 += v6.y;
    e0 += v7.x; e1 += v7.y;
  }
  for (; i < d; ++i) {
    int s = srcSorted[start + i];
    uint32_t u = Xl[(size_t)s << 6];
    f32x2 v = __builtin_amdgcn_cvt_pk_f32_fp8(u, false);
    a0 += v.x; a1 += v.y;
  }
  float s0 = (a0 + b0) + (c0 + e0);
  float s1 = (a1 + b1) + (c1 + e1);
  float scale = (d > 0) ? (1.0f / (float)d) : 0.0f;
  Ah[(size_t)wid * 64 + lane] = f2bf(s0 * scale) | (f2bf(s1 * scale) << 16);
}

// ---------------- MFMA GEMM: out = (x + A) @ Wt^T + bias ----------------
// LAYER=1: x from f32 X; writes bf16 h1 (outH) + fp8 h1 (outQ), RELU.
// LAYER=2: x from bf16 Hh; writes f32 d_out.

template <int LAYER>
__global__ __launch_bounds__(256) void gemm_mfma(const float* __restrict__ Xf,
                                                 const uint32_t* __restrict__ Xb,
                                                 const uint32_t* __restrict__ Ab,
                                                 const uint32_t* __restrict__ Wt,
                                                 const float* __restrict__ bias,
                                                 float* __restrict__ outF,
                                                 uint32_t* __restrict__ outH,
                                                 uint8_t* __restrict__ outQ, int N) {
  __shared__ short HS[64 * GP];
  __shared__ short WS[128 * GP];
  int t = threadIdx.x;
  int vbase = blockIdx.x * 64;

  // stage Wt (16B chunks): 2048 chunks of 8 shorts
  for (int c = t; c < 2048; c += 256) {
    int row = c >> 4, col8 = (c & 15) * 8;
    uint4 w = *(const uint4*)&Wt[row * 64 + (col8 >> 1)];
    *(uint4*)&WS[row * GP + col8] = w;
  }
  // stage h = x + A as bf16
  if (LAYER == 1) {
    for (int i = t; i < 2048; i += 256) {  // 64 rows x 32 float4
      int row = i >> 5, c4 = (i & 31) * 4;
      int v = vbase + row;
      uint2 hv = make_uint2(0, 0);
      if (v < N) {
        float4 xv = *(const float4*)&Xf[(size_t)v * FEATS + c4];
        uint2 au = *(const uint2*)&Ab[(size_t)v * 64 + (c4 >> 1)];
        hv.x = f2bf(xv.x + bflo(au.x)) | (f2bf(xv.y + bfhi(au.x)) << 16);
        hv.y = f2bf(xv.z + bflo(au.y)) | (f2bf(xv.w + bfhi(au.y)) << 16);
      }
      *(uint2*)&HS[row * GP + c4] = hv;
    }
  } else {
    for (int i = t; i < 4096; i += 256) {  // 64 rows x 64 dwords
      int row = i >> 6, c = i & 63;
      int v = vbase + row;
      uint32_t hv = 0;
      if (v < N) {
        uint32_t xu = Xb[(size_t)v * 64 + c];
        uint32_t au = Ab[(size_t)v * 64 + c];
        hv = f2bf(bflo(xu) + bflo(au)) | (f2bf(bfhi(xu) + bfhi(au)) << 16);
      }
      *(uint32_t*)&HS[row * GP + c * 2] = hv;
    }
  }
  __syncthreads();

  int wave = t >> 6, l = t & 63;
  int wr = wave * 16;                    // wave's 16 output rows
  int lr = l & 15, lk = (l >> 4) * 8;    // fragment index / k offset

  f32x4 acc[8];
#pragma unroll
  for (int i = 0; i < 8; ++i) acc[i] = (f32x4){0.f, 0.f, 0.f, 0.f};

#pragma unroll
  for (int ks = 0; ks < 4; ++ks) {
    int k0 = ks * 32 + lk;
    bf16x8 a = *(const bf16x8*)&HS[(wr + lr) * GP + k0];
#pragma unroll
    for (int nf = 0; nf < 8; ++nf) {
      bf16x8 b = *(const bf16x8*)&WS[(nf * 16 + lr) * GP + k0];
      acc[nf] = __builtin_amdgcn_mfma_f32_16x16x32_bf16(a, b, acc[nf], 0, 0, 0);
    }
  }

  // epilogue: D col = lane&15, row = (lane>>4)*4 + j
  int orow = wr + (l >> 4) * 4;
#pragma unroll
  for (int nf = 0; nf < 8; ++nf) {
    int col = nf * 16 + lr;
    float bv = bias[col];
#pragma unroll
    for (int j = 0; j < 4; ++j) {
      int v = vbase + orow + j;
      if (v < N) {
        float o = acc[nf][j] + bv;
        if (LAYER == 1) {
          o = fmaxf(o, 0.f);
          ((uint16_t*)outH)[(size_t)v * FEATS + col] = (uint16_t)f2bf(o);
          outQ[(size_t)v * FEATS + col] =
              (uint8_t)(__builtin_amdgcn_cvt_pk_fp8_f32(o, o, 0, false) & 0xffu);
        } else {
          outF[(size_t)v * FEATS + col] = o;
        }
      }
    }
  }
}

// ---------------- launcher ----------------

extern "C" void kernel_launch(void* const* d_in, const int* in_sizes, int n_in,
                              void* d_out, int out_size, void* d_ws, size_t ws_size,
                              hipStream_t stream) {
  const float* X = (const float*)d_in[0];
  const int* src = (const int*)d_in[1];
  const int* dst = (const int*)d_in[2];
  const float* W1 = (const float*)d_in[3];
  const float* b1 = (const float*)d_in[4];
  const float* W2 = (const float*)d_in[5];
  const float* b2 = (const float*)d_in[6];
  float* out = (float*)d_out;

  int N = in_sizes[0] / FEATS;
  int E = in_sizes[1];
  int NB = (N + 255) / 256;  // dst-page buckets

  char* ws = (char*)d_ws;
  auto alloc = [&](size_t bytes) -> char* {
    char* p = ws;
    ws += (bytes + 255) & ~(size_t)255;
    return p;
  };
  int* deg = (int*)alloc((size_t)N * 4);
  int* off = (int*)alloc((size_t)N * 4);
  int* bucketTotal = (int*)alloc((size_t)NB_MAX * 4);
  int* bucketBase = (int*)alloc((size_t)(NB_MAX + 1) * 4);
  int* bucketCursor = (int*)alloc((size_t)NB_MAX * 4);
  uint32_t* pairs = (uint32_t*)alloc((size_t)E * 4);
  int* srcSorted = (int*)alloc((size_t)E * 4);
  uint32_t* Xq = (uint32_t*)alloc((size_t)N * 32 * 4);  // fp8 X; becomes fp8 h1 after gemm1 (alias)
  uint32_t* Ah = (uint32_t*)alloc((size_t)N * 64 * 4);  // bf16 aggregate
  uint32_t* Hh = (uint32_t*)alloc((size_t)N * 64 * 4);  // bf16 h1
  uint32_t* Wt1 = (uint32_t*)alloc((size_t)64 * 128 * 4);
  uint32_t* Wt2 = (uint32_t*)alloc((size_t)64 * 128 * 4);
  uint32_t* Hq = Xq;  // safe alias: Xq fully consumed by agg1 before gemm1 writes Hq

  // ---- CSR build (no global per-node atomics anywhere) ----
  hipMemsetAsync(bucketTotal, 0, (size_t)NB_MAX * 4, stream);
  bucket_hist_kernel<<<256, 256, 0, stream>>>(dst, bucketTotal, E, NB);
  bucket_scan_kernel<<<1, NB_MAX, 0, stream>>>(bucketTotal, bucketBase, bucketCursor, NB);
  pairscatter_kernel<<<(E + PS_CHUNK - 1) / PS_CHUNK, PS_B, 0, stream>>>(src, dst, bucketCursor,
                                                                         pairs, E);
  fused_final_kernel<<<NB, 256, 0, stream>>>(pairs, bucketBase, deg, off, srcSorted, N);

  // ---- fp8 cast of X + weight transpose ----
  int nq = N * 32;
  cast_kernel<<<2048, 256, 0, stream>>>(X, Xq, nq);
  wtrans_kernel<<<2, 256, 0, stream>>>(W1, W2, Wt1, Wt2);

  int aggBlocks = (N + 3) / 4;
  int gb = (N + 63) / 64;

  // ---- layer 1: Ah = agg_fp8(Xq); Hh/Hq = relu((X+Ah)@W1+b1) ----
  agg_kernel<<<aggBlocks, 256, 0, stream>>>((const uint16_t*)Xq, srcSorted, off, deg, Ah, N);
  gemm_mfma<1><<<gb, 256, 0, stream>>>(X, nullptr, Ah, Wt1, b1, nullptr, Hh, (uint8_t*)Hq, N);

  // ---- layer 2: Ah = agg_fp8(Hq); out = (Hh+Ah)@W2+b2 (f32) ----
  agg_kernel<<<aggBlocks, 256, 0, stream>>>((const uint16_t*)Hq, srcSorted, off, deg, Ah, N);
  gemm_mfma<2><<<gb, 256, 0, stream>>>(nullptr, Hh, Ah, Wt2, b2, out, nullptr, nullptr, N);
}

// Round 7
// 240.560 us; speedup vs baseline: 2.7150x; 1.1491x over previous
//
#include <hip/hip_runtime.h>
#include <hip/hip_bf16.h>
#include <stdint.h>

#define FEATS 128
#define NB_MAX 512        // max buckets (supports N <= 131072)
#define PS_B 1024         // pair-scatter block threads
#define PS_EPT 16         // edges per thread
#define PS_CHUNK (PS_B * PS_EPT)
#define GP 136            // GEMM LDS pitch in shorts (272 B rows: 16B-aligned, 2-way max conflict)

typedef short bf16x8 __attribute__((ext_vector_type(8)));
typedef float f32x4 __attribute__((ext_vector_type(4)));
typedef float f32x2 __attribute__((ext_vector_type(2)));

// ---------------- helpers ----------------

__device__ inline uint32_t f2bf(float f) {  // RTNE f32 -> bf16 (low 16 bits)
  uint32_t x = __float_as_uint(f);
  uint32_t r = ((x >> 16) & 1u) + 0x7fffu;
  return (x + r) >> 16;
}
__device__ inline float bflo(uint32_t u) { return __uint_as_float(u << 16); }
__device__ inline float bfhi(uint32_t u) { return __uint_as_float(u & 0xffff0000u); }

// ---------------- cast: f32 -> fp8 e4m3 of X (pure streaming) ----------------

__global__ void cast_kernel(const float* __restrict__ X, uint32_t* __restrict__ Xq, int nq) {
  int i = blockIdx.x * blockDim.x + threadIdx.x;
  int stride = gridDim.x * blockDim.x;
  for (; i < nq; i += stride) {  // nq = N*32 (4 feats per u32)
    float4 v = ((const float4*)X)[i];
    uint32_t q = __builtin_amdgcn_cvt_pk_fp8_f32(v.x, v.y, 0, false);
    q = __builtin_amdgcn_cvt_pk_fp8_f32(v.z, v.w, q, true);
    Xq[i] = q;
  }
}

// ---------------- bucket histogram: LDS 512-bin, 1 global atomic per (block,bin) ----------------

__global__ void bucket_hist_kernel(const int* __restrict__ dst, int* __restrict__ bucketTotal,
                                   int E, int NB) {
  __shared__ int lh[NB_MAX];
  int t = threadIdx.x;
  for (int i = t; i < NB_MAX; i += 256) lh[i] = 0;
  __syncthreads();
  int i = blockIdx.x * blockDim.x + t;
  int stride = gridDim.x * blockDim.x;
  for (; i < E; i += stride) atomicAdd(&lh[dst[i] >> 8], 1);
  __syncthreads();
  for (int b = t; b < NB; b += 256) {
    int v = lh[b];
    if (v) atomicAdd(&bucketTotal[b], v);
  }
}

// ---------------- bucket scan: exclusive scan of bucket totals ----------------

__global__ void bucket_scan_kernel(const int* __restrict__ bucketTotal, int* __restrict__ bucketBase,
                                   int* __restrict__ bucketCursor, int NB) {
  __shared__ int s[NB_MAX];
  int t = threadIdx.x;
  int v = (t < NB) ? bucketTotal[t] : 0;
  s[t] = v;
  __syncthreads();
  for (int o = 1; o < NB_MAX; o <<= 1) {
    int add = (t >= o) ? s[t - o] : 0;
    __syncthreads();
    s[t] += add;
    __syncthreads();
  }
  if (t < NB) {
    int ex = s[t] - v;
    bucketBase[t] = ex;
    bucketCursor[t] = ex;
    if (t == NB - 1) bucketBase[NB] = s[t];  // = E
  }
}

// ---- pass 2: multisplit packed (src<<8 | dst&255) into dst-page buckets ----
__global__ __launch_bounds__(PS_B) void pairscatter_kernel(const int* __restrict__ src,
                                                           const int* __restrict__ dst,
                                                           int* __restrict__ bucketCursor,
                                                           uint32_t* __restrict__ pairs, int E) {
  __shared__ int hist[NB_MAX];
  __shared__ int rank[NB_MAX];
  __shared__ int res[NB_MAX];
  int t = threadIdx.x;
  int base = blockIdx.x * PS_CHUNK;

  if (t < NB_MAX) {
    hist[t] = 0;
    rank[t] = 0;
  }
  __syncthreads();

  int sr[PS_EPT], dr[PS_EPT];
#pragma unroll
  for (int j = 0; j < PS_EPT; ++j) {
    int i = base + j * PS_B + t;
    if (i < E) {
      sr[j] = src[i];
      dr[j] = dst[i];
      atomicAdd(&hist[dr[j] >> 8], 1);
    } else {
      dr[j] = -1;
    }
  }
  __syncthreads();

  if (t < NB_MAX) {
    int h = hist[t];
    res[t] = h ? atomicAdd(&bucketCursor[t], h) : 0;
  }
  __syncthreads();

#pragma unroll
  for (int j = 0; j < PS_EPT; ++j) {
    if (dr[j] >= 0) {
      int b = dr[j] >> 8;
      int r = atomicAdd(&rank[b], 1);
      pairs[(size_t)(res[b] + r)] = ((uint32_t)sr[j] << 8) | ((uint32_t)dr[j] & 255u);
    }
  }
}

// ---- fused final: per-bucket degree count (LDS) + scan (LDS) + deg/off write + scatter ----
__global__ __launch_bounds__(256) void fused_final_kernel(const uint32_t* __restrict__ pairs,
                                                          const int* __restrict__ bucketBase,
                                                          int* __restrict__ deg,
                                                          int* __restrict__ off,
                                                          int* __restrict__ srcSorted, int N) {
  __shared__ int cnt[256];
  __shared__ int scn[256];
  __shared__ int cur[256];
  int b = blockIdx.x, t = threadIdx.x;
  int bs = bucketBase[b], be = bucketBase[b + 1];
  cnt[t] = 0;
  __syncthreads();
  for (int i = bs + t; i < be; i += 256) atomicAdd(&cnt[pairs[i] & 255u], 1);
  __syncthreads();
  int v = cnt[t];
  scn[t] = v;
  __syncthreads();
  for (int o = 1; o < 256; o <<= 1) {
    int add = (t >= o) ? scn[t - o] : 0;
    __syncthreads();
    scn[t] += add;
    __syncthreads();
  }
  int myoff = bs + scn[t] - v;
  int node = b * 256 + t;
  if (node < N) {
    deg[node] = v;
    off[node] = myoff;
  }
  cur[t] = myoff;
  __syncthreads();
  for (int i = bs + t; i < be; i += 256) {
    uint32_t p = pairs[i];
    int pos = atomicAdd(&cur[p & 255u], 1);
    srcSorted[pos] = (int)(p >> 8);
  }
}

// ---------------- W [K=128][N=128] f32 -> Wt [n][k] bf16 packed (2 matrices, 2 blocks) ----------------

__global__ void wtrans_kernel(const float* __restrict__ W1, const float* __restrict__ W2,
                              uint32_t* __restrict__ Wt1, uint32_t* __restrict__ Wt2) {
  __shared__ uint16_t s[128 * 129];
  const float* W = blockIdx.x ? W2 : W1;
  uint32_t* Wt = blockIdx.x ? Wt2 : Wt1;
  int t = threadIdx.x;
  for (int i = t; i < 16384; i += 256) {
    int k = i >> 7, n = i & 127;
    s[n * 129 + k] = (uint16_t)f2bf(W[i]);
  }
  __syncthreads();
  for (int i = t; i < 8192; i += 256) {
    int n = i >> 6, kd = i & 63;
    uint32_t lo = s[n * 129 + kd * 2];
    uint32_t hi = s[n * 129 + kd * 2 + 1];
    Wt[i] = lo | (hi << 16);
  }
}

// ---- mean aggregation: one wave per node; 16 lanes per row (8B/lane), 4 edges per gather instr ----

__global__ void agg_kernel(const uint32_t* __restrict__ Xq, const int* __restrict__ srcSorted,
                           const int* __restrict__ off, const int* __restrict__ deg,
                           uint32_t* __restrict__ Ah, int N) {
  int wid = (int)((blockIdx.x * (unsigned)blockDim.x + threadIdx.x) >> 6);
  int lane = threadIdx.x & 63;
  if (wid >= N) return;
  int start = off[wid];
  int d = deg[wid];
  int g = lane >> 4;    // edge slot 0..3
  int lc = lane & 15;   // 8-feat column group; u32 offset lc*2 within the 32-u32 row

  float a0 = 0.f, a1 = 0.f, a2 = 0.f, a3 = 0.f, a4 = 0.f, a5 = 0.f, a6 = 0.f, a7 = 0.f;

  for (int base = 0; base < d; base += 64) {
    int nIdx = min(64, d - base);
    int myIdx = (lane < nIdx) ? srcSorted[start + base + lane] : 0;
    int e = 0;
    for (; e + 8 <= nIdx; e += 8) {  // 2 independent 4-edge gathers
      int r0 = __shfl(myIdx, e + g);
      int r1 = __shfl(myIdx, e + 4 + g);
      uint2 ua = *(const uint2*)(Xq + ((size_t)r0 << 5) + lc * 2);
      uint2 ub = *(const uint2*)(Xq + ((size_t)r1 << 5) + lc * 2);
      f32x2 p0 = __builtin_amdgcn_cvt_pk_f32_fp8(ua.x, false);
      f32x2 p1 = __builtin_amdgcn_cvt_pk_f32_fp8(ua.x, true);
      f32x2 p2 = __builtin_amdgcn_cvt_pk_f32_fp8(ua.y, false);
      f32x2 p3 = __builtin_amdgcn_cvt_pk_f32_fp8(ua.y, true);
      f32x2 q0 = __builtin_amdgcn_cvt_pk_f32_fp8(ub.x, false);
      f32x2 q1 = __builtin_amdgcn_cvt_pk_f32_fp8(ub.x, true);
      f32x2 q2 = __builtin_amdgcn_cvt_pk_f32_fp8(ub.y, false);
      f32x2 q3 = __builtin_amdgcn_cvt_pk_f32_fp8(ub.y, true);
      a0 += p0.x + q0.x; a1 += p0.y + q0.y;
      a2 += p1.x + q1.x; a3 += p1.y + q1.y;
      a4 += p2.x + q2.x; a5 += p2.y + q2.y;
      a6 += p3.x + q3.x; a7 += p3.y + q3.y;
    }
    if (e + 4 <= nIdx) {
      int r0 = __shfl(myIdx, e + g);
      uint2 ua = *(const uint2*)(Xq + ((size_t)r0 << 5) + lc * 2);
      f32x2 p0 = __builtin_amdgcn_cvt_pk_f32_fp8(ua.x, false);
      f32x2 p1 = __builtin_amdgcn_cvt_pk_f32_fp8(ua.x, true);
      f32x2 p2 = __builtin_amdgcn_cvt_pk_f32_fp8(ua.y, false);
      f32x2 p3 = __builtin_amdgcn_cvt_pk_f32_fp8(ua.y, true);
      a0 += p0.x; a1 += p0.y; a2 += p1.x; a3 += p1.y;
      a4 += p2.x; a5 += p2.y; a6 += p3.x; a7 += p3.y;
      e += 4;
    }
    int rem = nIdx - e;
    if (rem) {
      int sl = e + g;
      int r0 = __shfl(myIdx, (sl < nIdx) ? sl : e);
      uint2 ua = *(const uint2*)(Xq + ((size_t)r0 << 5) + lc * 2);
      float m = (g < rem) ? 1.f : 0.f;
      f32x2 p0 = __builtin_amdgcn_cvt_pk_f32_fp8(ua.x, false);
      f32x2 p1 = __builtin_amdgcn_cvt_pk_f32_fp8(ua.x, true);
      f32x2 p2 = __builtin_amdgcn_cvt_pk_f32_fp8(ua.y, false);
      f32x2 p3 = __builtin_amdgcn_cvt_pk_f32_fp8(ua.y, true);
      a0 = fmaf(m, p0.x, a0); a1 = fmaf(m, p0.y, a1);
      a2 = fmaf(m, p1.x, a2); a3 = fmaf(m, p1.y, a3);
      a4 = fmaf(m, p2.x, a4); a5 = fmaf(m, p2.y, a5);
      a6 = fmaf(m, p3.x, a6); a7 = fmaf(m, p3.y, a7);
    }
  }

  // reduce across the 4 edge-slot lane groups (lanes l, l+16, l+32, l+48)
  a0 += __shfl_xor(a0, 32); a1 += __shfl_xor(a1, 32);
  a2 += __shfl_xor(a2, 32); a3 += __shfl_xor(a3, 32);
  a4 += __shfl_xor(a4, 32); a5 += __shfl_xor(a5, 32);
  a6 += __shfl_xor(a6, 32); a7 += __shfl_xor(a7, 32);
  a0 += __shfl_xor(a0, 16); a1 += __shfl_xor(a1, 16);
  a2 += __shfl_xor(a2, 16); a3 += __shfl_xor(a3, 16);
  a4 += __shfl_xor(a4, 16); a5 += __shfl_xor(a5, 16);
  a6 += __shfl_xor(a6, 16); a7 += __shfl_xor(a7, 16);

  if (g == 0) {
    float scale = (d > 0) ? (1.0f / (float)d) : 0.0f;
    uint4 o;
    o.x = f2bf(a0 * scale) | (f2bf(a1 * scale) << 16);
    o.y = f2bf(a2 * scale) | (f2bf(a3 * scale) << 16);
    o.z = f2bf(a4 * scale) | (f2bf(a5 * scale) << 16);
    o.w = f2bf(a6 * scale) | (f2bf(a7 * scale) << 16);
    *(uint4*)&Ah[(size_t)wid * 64 + lc * 4] = o;
  }
}

// ---------------- MFMA GEMM: out = (x + A) @ Wt^T + bias ----------------
// LAYER=1: x from f32 X; writes bf16 h1 (outH) + fp8 h1 (outQ), RELU.
// LAYER=2: x from bf16 Hh; writes f32 d_out.

template <int LAYER>
__global__ __launch_bounds__(256) void gemm_mfma(const float* __restrict__ Xf,
                                                 const uint32_t* __restrict__ Xb,
                                                 const uint32_t* __restrict__ Ab,
                                                 const uint32_t* __restrict__ Wt,
                                                 const float* __restrict__ bias,
                                                 float* __restrict__ outF,
                                                 uint32_t* __restrict__ outH,
                                                 uint8_t* __restrict__ outQ, int N) {
  __shared__ short HS[64 * GP];
  __shared__ short WS[128 * GP];
  int t = threadIdx.x;
  int vbase = blockIdx.x * 64;

  // stage Wt (16B chunks): 2048 chunks of 8 shorts
  for (int c = t; c < 2048; c += 256) {
    int row = c >> 4, col8 = (c & 15) * 8;
    uint4 w = *(const uint4*)&Wt[row * 64 + (col8 >> 1)];
    *(uint4*)&WS[row * GP + col8] = w;
  }
  // stage h = x + A as bf16
  if (LAYER == 1) {
    for (int i = t; i < 2048; i += 256) {  // 64 rows x 32 float4
      int row = i >> 5, c4 = (i & 31) * 4;
      int v = vbase + row;
      uint2 hv = make_uint2(0, 0);
      if (v < N) {
        float4 xv = *(const float4*)&Xf[(size_t)v * FEATS + c4];
        uint2 au = *(const uint2*)&Ab[(size_t)v * 64 + (c4 >> 1)];
        hv.x = f2bf(xv.x + bflo(au.x)) | (f2bf(xv.y + bfhi(au.x)) << 16);
        hv.y = f2bf(xv.z + bflo(au.y)) | (f2bf(xv.w + bfhi(au.y)) << 16);
      }
      *(uint2*)&HS[row * GP + c4] = hv;
    }
  } else {
    for (int i = t; i < 4096; i += 256) {  // 64 rows x 64 dwords
      int row = i >> 6, c = i & 63;
      int v = vbase + row;
      uint32_t hv = 0;
      if (v < N) {
        uint32_t xu = Xb[(size_t)v * 64 + c];
        uint32_t au = Ab[(size_t)v * 64 + c];
        hv = f2bf(bflo(xu) + bflo(au)) | (f2bf(bfhi(xu) + bfhi(au)) << 16);
      }
      *(uint32_t*)&HS[row * GP + c * 2] = hv;
    }
  }
  __syncthreads();

  int wave = t >> 6, l = t & 63;
  int wr = wave * 16;                    // wave's 16 output rows
  int lr = l & 15, lk = (l >> 4) * 8;    // fragment index / k offset

  f32x4 acc[8];
#pragma unroll
  for (int i = 0; i < 8; ++i) acc[i] = (f32x4){0.f, 0.f, 0.f, 0.f};

#pragma unroll
  for (int ks = 0; ks < 4; ++ks) {
    int k0 = ks * 32 + lk;
    bf16x8 a = *(const bf16x8*)&HS[(wr + lr) * GP + k0];
#pragma unroll
    for (int nf = 0; nf < 8; ++nf) {
      bf16x8 b = *(const bf16x8*)&WS[(nf * 16 + lr) * GP + k0];
      acc[nf] = __builtin_amdgcn_mfma_f32_16x16x32_bf16(a, b, acc[nf], 0, 0, 0);
    }
  }

  // epilogue: D col = lane&15, row = (lane>>4)*4 + j
  int orow = wr + (l >> 4) * 4;
#pragma unroll
  for (int nf = 0; nf < 8; ++nf) {
    int col = nf * 16 + lr;
    float bv = bias[col];
#pragma unroll
    for (int j = 0; j < 4; ++j) {
      int v = vbase + orow + j;
      if (v < N) {
        float o = acc[nf][j] + bv;
        if (LAYER == 1) {
          o = fmaxf(o, 0.f);
          ((uint16_t*)outH)[(size_t)v * FEATS + col] = (uint16_t)f2bf(o);
          outQ[(size_t)v * FEATS + col] =
              (uint8_t)(__builtin_amdgcn_cvt_pk_fp8_f32(o, o, 0, false) & 0xffu);
        } else {
          outF[(size_t)v * FEATS + col] = o;
        }
      }
    }
  }
}

// ---------------- launcher ----------------

extern "C" void kernel_launch(void* const* d_in, const int* in_sizes, int n_in,
                              void* d_out, int out_size, void* d_ws, size_t ws_size,
                              hipStream_t stream) {
  const float* X = (const float*)d_in[0];
  const int* src = (const int*)d_in[1];
  const int* dst = (const int*)d_in[2];
  const float* W1 = (const float*)d_in[3];
  const float* b1 = (const float*)d_in[4];
  const float* W2 = (const float*)d_in[5];
  const float* b2 = (const float*)d_in[6];
  float* out = (float*)d_out;

  int N = in_sizes[0] / FEATS;
  int E = in_sizes[1];
  int NB = (N + 255) / 256;  // dst-page buckets

  char* ws = (char*)d_ws;
  auto alloc = [&](size_t bytes) -> char* {
    char* p = ws;
    ws += (bytes + 255) & ~(size_t)255;
    return p;
  };
  int* deg = (int*)alloc((size_t)N * 4);
  int* off = (int*)alloc((size_t)N * 4);
  int* bucketTotal = (int*)alloc((size_t)NB_MAX * 4);
  int* bucketBase = (int*)alloc((size_t)(NB_MAX + 1) * 4);
  int* bucketCursor = (int*)alloc((size_t)NB_MAX * 4);
  uint32_t* pairs = (uint32_t*)alloc((size_t)E * 4);
  int* srcSorted = (int*)alloc((size_t)E * 4);
  uint32_t* Xq = (uint32_t*)alloc((size_t)N * 32 * 4);  // fp8 X; becomes fp8 h1 after gemm1 (alias)
  uint32_t* Ah = (uint32_t*)alloc((size_t)N * 64 * 4);  // bf16 aggregate
  uint32_t* Hh = (uint32_t*)alloc((size_t)N * 64 * 4);  // bf16 h1
  uint32_t* Wt1 = (uint32_t*)alloc((size_t)64 * 128 * 4);
  uint32_t* Wt2 = (uint32_t*)alloc((size_t)64 * 128 * 4);
  uint32_t* Hq = Xq;  // safe alias: Xq fully consumed by agg1 before gemm1 writes Hq

  // ---- CSR build (no global per-node atomics anywhere) ----
  hipMemsetAsync(bucketTotal, 0, (size_t)NB_MAX * 4, stream);
  bucket_hist_kernel<<<256, 256, 0, stream>>>(dst, bucketTotal, E, NB);
  bucket_scan_kernel<<<1, NB_MAX, 0, stream>>>(bucketTotal, bucketBase, bucketCursor, NB);
  pairscatter_kernel<<<(E + PS_CHUNK - 1) / PS_CHUNK, PS_B, 0, stream>>>(src, dst, bucketCursor,
                                                                         pairs, E);
  fused_final_kernel<<<NB, 256, 0, stream>>>(pairs, bucketBase, deg, off, srcSorted, N);

  // ---- fp8 cast of X + weight transpose ----
  int nq = N * 32;
  cast_kernel<<<2048, 256, 0, stream>>>(X, Xq, nq);
  wtrans_kernel<<<2, 256, 0, stream>>>(W1, W2, Wt1, Wt2);

  int aggBlocks = (N + 3) / 4;
  int gb = (N + 63) / 64;

  // ---- layer 1: Ah = agg_fp8(Xq); Hh/Hq = relu((X+Ah)@W1+b1) ----
  agg_kernel<<<aggBlocks, 256, 0, stream>>>(Xq, srcSorted, off, deg, Ah, N);
  gemm_mfma<1><<<gb, 256, 0, stream>>>(X, nullptr, Ah, Wt1, b1, nullptr, Hh, (uint8_t*)Hq, N);

  // ---- layer 2: Ah = agg_fp8(Hq); out = (Hh+Ah)@W2+b2 (f32) ----
  agg_kernel<<<aggBlocks, 256, 0, stream>>>(Hq, srcSorted, off, deg, Ah, N);
  gemm_mfma<2><<<gb, 256, 0, stream>>>(nullptr, Hh, Ah, Wt2, b2, out, nullptr, nullptr, N);
}

// Round 8
// 236.672 us; speedup vs baseline: 2.7596x; 1.0164x over previous
//
#include <hip/hip_runtime.h>
#include <hip/hip_bf16.h>
#include <stdint.h>

#define FEATS 128
#define NB_MAX 512        // max buckets (supports N <= 131072)
#define PS_B 1024         // pair-scatter block threads
#define PS_EPT 16         // edges per thread
#define PS_CHUNK (PS_B * PS_EPT)
#define GP 136            // GEMM LDS pitch in shorts (272 B rows: 16B-aligned, 2-way max conflict)

typedef short bf16x8 __attribute__((ext_vector_type(8)));
typedef float f32x4 __attribute__((ext_vector_type(4)));
typedef float f32x2 __attribute__((ext_vector_type(2)));

// ---------------- helpers ----------------

__device__ inline uint32_t f2bf(float f) {  // RTNE f32 -> bf16 (low 16 bits)
  uint32_t x = __float_as_uint(f);
  uint32_t r = ((x >> 16) & 1u) + 0x7fffu;
  return (x + r) >> 16;
}
__device__ inline float bflo(uint32_t u) { return __uint_as_float(u << 16); }
__device__ inline float bfhi(uint32_t u) { return __uint_as_float(u & 0xffff0000u); }

__device__ inline f32x2 sx2(f32x2 v, int m) {
  f32x2 r;
  r.x = __shfl_xor(v.x, m);
  r.y = __shfl_xor(v.y, m);
  return r;
}

// ---------------- cast: f32 -> fp8 e4m3 of X (pure streaming) ----------------

__global__ void cast_kernel(const float* __restrict__ X, uint32_t* __restrict__ Xq, int nq) {
  int i = blockIdx.x * blockDim.x + threadIdx.x;
  int stride = gridDim.x * blockDim.x;
  for (; i < nq; i += stride) {  // nq = N*32 (4 feats per u32)
    float4 v = ((const float4*)X)[i];
    uint32_t q = __builtin_amdgcn_cvt_pk_fp8_f32(v.x, v.y, 0, false);
    q = __builtin_amdgcn_cvt_pk_fp8_f32(v.z, v.w, q, true);
    Xq[i] = q;
  }
}

// ---------------- bucket histogram: LDS 512-bin, 1 global atomic per (block,bin) ----------------

__global__ void bucket_hist_kernel(const int* __restrict__ dst, int* __restrict__ bucketTotal,
                                   int E, int NB) {
  __shared__ int lh[NB_MAX];
  int t = threadIdx.x;
  for (int i = t; i < NB_MAX; i += 256) lh[i] = 0;
  __syncthreads();
  int i = blockIdx.x * blockDim.x + t;
  int stride = gridDim.x * blockDim.x;
  for (; i < E; i += stride) atomicAdd(&lh[dst[i] >> 8], 1);
  __syncthreads();
  for (int b = t; b < NB; b += 256) {
    int v = lh[b];
    if (v) atomicAdd(&bucketTotal[b], v);
  }
}

// ---------------- bucket scan: exclusive scan of bucket totals ----------------

__global__ void bucket_scan_kernel(const int* __restrict__ bucketTotal, int* __restrict__ bucketBase,
                                   int* __restrict__ bucketCursor, int NB) {
  __shared__ int s[NB_MAX];
  int t = threadIdx.x;
  int v = (t < NB) ? bucketTotal[t] : 0;
  s[t] = v;
  __syncthreads();
  for (int o = 1; o < NB_MAX; o <<= 1) {
    int add = (t >= o) ? s[t - o] : 0;
    __syncthreads();
    s[t] += add;
    __syncthreads();
  }
  if (t < NB) {
    int ex = s[t] - v;
    bucketBase[t] = ex;
    bucketCursor[t] = ex;
    if (t == NB - 1) bucketBase[NB] = s[t];  // = E
  }
}

// ---- pass 2: multisplit packed (src<<8 | dst&255) into dst-page buckets ----
__global__ __launch_bounds__(PS_B) void pairscatter_kernel(const int* __restrict__ src,
                                                           const int* __restrict__ dst,
                                                           int* __restrict__ bucketCursor,
                                                           uint32_t* __restrict__ pairs, int E) {
  __shared__ int hist[NB_MAX];
  __shared__ int rank[NB_MAX];
  __shared__ int res[NB_MAX];
  int t = threadIdx.x;
  int base = blockIdx.x * PS_CHUNK;

  if (t < NB_MAX) {
    hist[t] = 0;
    rank[t] = 0;
  }
  __syncthreads();

  int sr[PS_EPT], dr[PS_EPT];
#pragma unroll
  for (int j = 0; j < PS_EPT; ++j) {
    int i = base + j * PS_B + t;
    if (i < E) {
      sr[j] = src[i];
      dr[j] = dst[i];
      atomicAdd(&hist[dr[j] >> 8], 1);
    } else {
      dr[j] = -1;
    }
  }
  __syncthreads();

  if (t < NB_MAX) {
    int h = hist[t];
    res[t] = h ? atomicAdd(&bucketCursor[t], h) : 0;
  }
  __syncthreads();

#pragma unroll
  for (int j = 0; j < PS_EPT; ++j) {
    if (dr[j] >= 0) {
      int b = dr[j] >> 8;
      int r = atomicAdd(&rank[b], 1);
      pairs[(size_t)(res[b] + r)] = ((uint32_t)sr[j] << 8) | ((uint32_t)dr[j] & 255u);
    }
  }
}

// ---- fused final: per-bucket degree count (LDS) + scan (LDS) + offdeg write + scatter ----
__global__ __launch_bounds__(256) void fused_final_kernel(const uint32_t* __restrict__ pairs,
                                                          const int* __restrict__ bucketBase,
                                                          int2* __restrict__ offdeg,
                                                          int* __restrict__ srcSorted, int N) {
  __shared__ int cnt[256];
  __shared__ int scn[256];
  __shared__ int cur[256];
  int b = blockIdx.x, t = threadIdx.x;
  int bs = bucketBase[b], be = bucketBase[b + 1];
  cnt[t] = 0;
  __syncthreads();
  for (int i = bs + t; i < be; i += 256) atomicAdd(&cnt[pairs[i] & 255u], 1);
  __syncthreads();
  int v = cnt[t];
  scn[t] = v;
  __syncthreads();
  for (int o = 1; o < 256; o <<= 1) {
    int add = (t >= o) ? scn[t - o] : 0;
    __syncthreads();
    scn[t] += add;
    __syncthreads();
  }
  int myoff = bs + scn[t] - v;
  int node = b * 256 + t;
  if (node < N) offdeg[node] = make_int2(myoff, v);
  cur[t] = myoff;
  __syncthreads();
  for (int i = bs + t; i < be; i += 256) {
    uint32_t p = pairs[i];
    int pos = atomicAdd(&cur[p & 255u], 1);
    srcSorted[pos] = (int)(p >> 8);
  }
}

// ---------------- W [K=128][N=128] f32 -> Wt [n][k] bf16 packed (2 matrices, 2 blocks) ----------------

__global__ void wtrans_kernel(const float* __restrict__ W1, const float* __restrict__ W2,
                              uint32_t* __restrict__ Wt1, uint32_t* __restrict__ Wt2) {
  __shared__ uint16_t s[128 * 129];
  const float* W = blockIdx.x ? W2 : W1;
  uint32_t* Wt = blockIdx.x ? Wt2 : Wt1;
  int t = threadIdx.x;
  for (int i = t; i < 16384; i += 256) {
    int k = i >> 7, n = i & 127;
    s[n * 129 + k] = (uint16_t)f2bf(W[i]);
  }
  __syncthreads();
  for (int i = t; i < 8192; i += 256) {
    int n = i >> 6, kd = i & 63;
    uint32_t lo = s[n * 129 + kd * 2];
    uint32_t hi = s[n * 129 + kd * 2 + 1];
    Wt[i] = lo | (hi << 16);
  }
}

// ---- mean aggregation: one wave per node; 16 lanes x 4 edge slots; direct broadcast idx loads ----

__global__ void agg_kernel(const uint32_t* __restrict__ Xq, const int* __restrict__ srcSorted,
                           const int2* __restrict__ offdeg, uint32_t* __restrict__ Ah, int N) {
  int wid = (int)((blockIdx.x * (unsigned)blockDim.x + threadIdx.x) >> 6);
  int lane = threadIdx.x & 63;
  if (wid >= N) return;
  int2 od = offdeg[wid];
  int start = od.x, d = od.y;
  int g = lane >> 4;    // edge slot 0..3
  int lc = lane & 15;   // 8-feat column group; u32 offset lc*2 within the 32-u32 row
  const int* idxp = srcSorted + start + g;
  const uint32_t* Xc = Xq + lc * 2;

  f32x2 a0 = {0.f, 0.f}, a1 = {0.f, 0.f}, a2 = {0.f, 0.f}, a3 = {0.f, 0.f};

  int e = 0;
  for (; e + 16 <= d; e += 16) {  // 4 independent idx loads + 4 independent gathers
    int i0 = idxp[e];
    int i1 = idxp[e + 4];
    int i2 = idxp[e + 8];
    int i3 = idxp[e + 12];
    uint2 ua = *(const uint2*)(Xc + ((size_t)i0 << 5));
    uint2 ub = *(const uint2*)(Xc + ((size_t)i1 << 5));
    uint2 uc = *(const uint2*)(Xc + ((size_t)i2 << 5));
    uint2 ud = *(const uint2*)(Xc + ((size_t)i3 << 5));
    a0 += __builtin_amdgcn_cvt_pk_f32_fp8(ua.x, false);
    a1 += __builtin_amdgcn_cvt_pk_f32_fp8(ua.x, true);
    a2 += __builtin_amdgcn_cvt_pk_f32_fp8(ua.y, false);
    a3 += __builtin_amdgcn_cvt_pk_f32_fp8(ua.y, true);
    a0 += __builtin_amdgcn_cvt_pk_f32_fp8(ub.x, false);
    a1 += __builtin_amdgcn_cvt_pk_f32_fp8(ub.x, true);
    a2 += __builtin_amdgcn_cvt_pk_f32_fp8(ub.y, false);
    a3 += __builtin_amdgcn_cvt_pk_f32_fp8(ub.y, true);
    a0 += __builtin_amdgcn_cvt_pk_f32_fp8(uc.x, false);
    a1 += __builtin_amdgcn_cvt_pk_f32_fp8(uc.x, true);
    a2 += __builtin_amdgcn_cvt_pk_f32_fp8(uc.y, false);
    a3 += __builtin_amdgcn_cvt_pk_f32_fp8(uc.y, true);
    a0 += __builtin_amdgcn_cvt_pk_f32_fp8(ud.x, false);
    a1 += __builtin_amdgcn_cvt_pk_f32_fp8(ud.x, true);
    a2 += __builtin_amdgcn_cvt_pk_f32_fp8(ud.y, false);
    a3 += __builtin_amdgcn_cvt_pk_f32_fp8(ud.y, true);
  }
  if (e + 8 <= d) {
    int i0 = idxp[e];
    int i1 = idxp[e + 4];
    uint2 ua = *(const uint2*)(Xc + ((size_t)i0 << 5));
    uint2 ub = *(const uint2*)(Xc + ((size_t)i1 << 5));
    a0 += __builtin_amdgcn_cvt_pk_f32_fp8(ua.x, false);
    a1 += __builtin_amdgcn_cvt_pk_f32_fp8(ua.x, true);
    a2 += __builtin_amdgcn_cvt_pk_f32_fp8(ua.y, false);
    a3 += __builtin_amdgcn_cvt_pk_f32_fp8(ua.y, true);
    a0 += __builtin_amdgcn_cvt_pk_f32_fp8(ub.x, false);
    a1 += __builtin_amdgcn_cvt_pk_f32_fp8(ub.x, true);
    a2 += __builtin_amdgcn_cvt_pk_f32_fp8(ub.y, false);
    a3 += __builtin_amdgcn_cvt_pk_f32_fp8(ub.y, true);
    e += 8;
  }
  if (e + 4 <= d) {
    int i0 = idxp[e];
    uint2 ua = *(const uint2*)(Xc + ((size_t)i0 << 5));
    a0 += __builtin_amdgcn_cvt_pk_f32_fp8(ua.x, false);
    a1 += __builtin_amdgcn_cvt_pk_f32_fp8(ua.x, true);
    a2 += __builtin_amdgcn_cvt_pk_f32_fp8(ua.y, false);
    a3 += __builtin_amdgcn_cvt_pk_f32_fp8(ua.y, true);
    e += 4;
  }
  int rem = d - e;  // 0..3
  if (g < rem) {    // exec-masked: only slots with a valid edge participate
    int i0 = idxp[e];
    uint2 ua = *(const uint2*)(Xc + ((size_t)i0 << 5));
    a0 += __builtin_amdgcn_cvt_pk_f32_fp8(ua.x, false);
    a1 += __builtin_amdgcn_cvt_pk_f32_fp8(ua.x, true);
    a2 += __builtin_amdgcn_cvt_pk_f32_fp8(ua.y, false);
    a3 += __builtin_amdgcn_cvt_pk_f32_fp8(ua.y, true);
  }

  // reduce across the 4 edge-slot lane groups (lanes l, l+16, l+32, l+48)
  a0 += sx2(a0, 32); a1 += sx2(a1, 32); a2 += sx2(a2, 32); a3 += sx2(a3, 32);
  a0 += sx2(a0, 16); a1 += sx2(a1, 16); a2 += sx2(a2, 16); a3 += sx2(a3, 16);

  if (g == 0) {
    float scale = (d > 0) ? (1.0f / (float)d) : 0.0f;
    uint4 o;
    o.x = f2bf(a0.x * scale) | (f2bf(a0.y * scale) << 16);
    o.y = f2bf(a1.x * scale) | (f2bf(a1.y * scale) << 16);
    o.z = f2bf(a2.x * scale) | (f2bf(a2.y * scale) << 16);
    o.w = f2bf(a3.x * scale) | (f2bf(a3.y * scale) << 16);
    *(uint4*)&Ah[(size_t)wid * 64 + lc * 4] = o;
  }
}

// ---------------- MFMA GEMM: out = (x + A) @ Wt^T + bias ----------------
// LAYER=1: x from f32 X; writes bf16 h1 (outH) + fp8 h1 (outQ), RELU.
// LAYER=2: x from bf16 Hh; writes f32 d_out.

template <int LAYER>
__global__ __launch_bounds__(256) void gemm_mfma(const float* __restrict__ Xf,
                                                 const uint32_t* __restrict__ Xb,
                                                 const uint32_t* __restrict__ Ab,
                                                 const uint32_t* __restrict__ Wt,
                                                 const float* __restrict__ bias,
                                                 float* __restrict__ outF,
                                                 uint32_t* __restrict__ outH,
                                                 uint8_t* __restrict__ outQ, int N) {
  __shared__ short HS[64 * GP];
  __shared__ short WS[128 * GP];
  int t = threadIdx.x;
  int vbase = blockIdx.x * 64;

  // stage Wt (16B chunks): 2048 chunks of 8 shorts
  for (int c = t; c < 2048; c += 256) {
    int row = c >> 4, col8 = (c & 15) * 8;
    uint4 w = *(const uint4*)&Wt[row * 64 + (col8 >> 1)];
    *(uint4*)&WS[row * GP + col8] = w;
  }
  // stage h = x + A as bf16
  if (LAYER == 1) {
    for (int i = t; i < 2048; i += 256) {  // 64 rows x 32 float4
      int row = i >> 5, c4 = (i & 31) * 4;
      int v = vbase + row;
      uint2 hv = make_uint2(0, 0);
      if (v < N) {
        float4 xv = *(const float4*)&Xf[(size_t)v * FEATS + c4];
        uint2 au = *(const uint2*)&Ab[(size_t)v * 64 + (c4 >> 1)];
        hv.x = f2bf(xv.x + bflo(au.x)) | (f2bf(xv.y + bfhi(au.x)) << 16);
        hv.y = f2bf(xv.z + bflo(au.y)) | (f2bf(xv.w + bfhi(au.y)) << 16);
      }
      *(uint2*)&HS[row * GP + c4] = hv;
    }
  } else {
    for (int i = t; i < 4096; i += 256) {  // 64 rows x 64 dwords
      int row = i >> 6, c = i & 63;
      int v = vbase + row;
      uint32_t hv = 0;
      if (v < N) {
        uint32_t xu = Xb[(size_t)v * 64 + c];
        uint32_t au = Ab[(size_t)v * 64 + c];
        hv = f2bf(bflo(xu) + bflo(au)) | (f2bf(bfhi(xu) + bfhi(au)) << 16);
      }
      *(uint32_t*)&HS[row * GP + c * 2] = hv;
    }
  }
  __syncthreads();

  int wave = t >> 6, l = t & 63;
  int wr = wave * 16;                    // wave's 16 output rows
  int lr = l & 15, lk = (l >> 4) * 8;    // fragment index / k offset

  f32x4 acc[8];
#pragma unroll
  for (int i = 0; i < 8; ++i) acc[i] = (f32x4){0.f, 0.f, 0.f, 0.f};

#pragma unroll
  for (int ks = 0; ks < 4; ++ks) {
    int k0 = ks * 32 + lk;
    bf16x8 a = *(const bf16x8*)&HS[(wr + lr) * GP + k0];
#pragma unroll
    for (int nf = 0; nf < 8; ++nf) {
      bf16x8 b = *(const bf16x8*)&WS[(nf * 16 + lr) * GP + k0];
      acc[nf] = __builtin_amdgcn_mfma_f32_16x16x32_bf16(a, b, acc[nf], 0, 0, 0);
    }
  }

  // epilogue: D col = lane&15, row = (lane>>4)*4 + j
  int orow = wr + (l >> 4) * 4;
#pragma unroll
  for (int nf = 0; nf < 8; ++nf) {
    int col = nf * 16 + lr;
    float bv = bias[col];
#pragma unroll
    for (int j = 0; j < 4; ++j) {
      int v = vbase + orow + j;
      if (v < N) {
        float o = acc[nf][j] + bv;
        if (LAYER == 1) {
          o = fmaxf(o, 0.f);
          ((uint16_t*)outH)[(size_t)v * FEATS + col] = (uint16_t)f2bf(o);
          outQ[(size_t)v * FEATS + col] =
              (uint8_t)(__builtin_amdgcn_cvt_pk_fp8_f32(o, o, 0, false) & 0xffu);
        } else {
          outF[(size_t)v * FEATS + col] = o;
        }
      }
    }
  }
}

// ---------------- launcher ----------------

extern "C" void kernel_launch(void* const* d_in, const int* in_sizes, int n_in,
                              void* d_out, int out_size, void* d_ws, size_t ws_size,
                              hipStream_t stream) {
  const float* X = (const float*)d_in[0];
  const int* src = (const int*)d_in[1];
  const int* dst = (const int*)d_in[2];
  const float* W1 = (const float*)d_in[3];
  const float* b1 = (const float*)d_in[4];
  const float* W2 = (const float*)d_in[5];
  const float* b2 = (const float*)d_in[6];
  float* out = (float*)d_out;

  int N = in_sizes[0] / FEATS;
  int E = in_sizes[1];
  int NB = (N + 255) / 256;  // dst-page buckets

  char* ws = (char*)d_ws;
  auto alloc = [&](size_t bytes) -> char* {
    char* p = ws;
    ws += (bytes + 255) & ~(size_t)255;
    return p;
  };
  int2* offdeg = (int2*)alloc((size_t)N * 8);
  int* bucketTotal = (int*)alloc((size_t)NB_MAX * 4);
  int* bucketBase = (int*)alloc((size_t)(NB_MAX + 1) * 4);
  int* bucketCursor = (int*)alloc((size_t)NB_MAX * 4);
  uint32_t* pairs = (uint32_t*)alloc((size_t)E * 4);
  int* srcSorted = (int*)alloc((size_t)E * 4);
  uint32_t* Xq = (uint32_t*)alloc((size_t)N * 32 * 4);  // fp8 X; becomes fp8 h1 after gemm1 (alias)
  uint32_t* Ah = (uint32_t*)alloc((size_t)N * 64 * 4);  // bf16 aggregate
  uint32_t* Hh = (uint32_t*)alloc((size_t)N * 64 * 4);  // bf16 h1
  uint32_t* Wt1 = (uint32_t*)alloc((size_t)64 * 128 * 4);
  uint32_t* Wt2 = (uint32_t*)alloc((size_t)64 * 128 * 4);
  uint32_t* Hq = Xq;  // safe alias: Xq fully consumed by agg1 before gemm1 writes Hq

  // ---- CSR build (no global per-node atomics anywhere) ----
  hipMemsetAsync(bucketTotal, 0, (size_t)NB_MAX * 4, stream);
  bucket_hist_kernel<<<256, 256, 0, stream>>>(dst, bucketTotal, E, NB);
  bucket_scan_kernel<<<1, NB_MAX, 0, stream>>>(bucketTotal, bucketBase, bucketCursor, NB);
  pairscatter_kernel<<<(E + PS_CHUNK - 1) / PS_CHUNK, PS_B, 0, stream>>>(src, dst, bucketCursor,
                                                                         pairs, E);
  fused_final_kernel<<<NB, 256, 0, stream>>>(pairs, bucketBase, offdeg, srcSorted, N);

  // ---- fp8 cast of X + weight transpose ----
  int nq = N * 32;
  cast_kernel<<<2048, 256, 0, stream>>>(X, Xq, nq);
  wtrans_kernel<<<2, 256, 0, stream>>>(W1, W2, Wt1, Wt2);

  int aggBlocks = (N + 3) / 4;
  int gb = (N + 63) / 64;

  // ---- layer 1: Ah = agg_fp8(Xq); Hh/Hq = relu((X+Ah)@W1+b1) ----
  agg_kernel<<<aggBlocks, 256, 0, stream>>>(Xq, srcSorted, offdeg, Ah, N);
  gemm_mfma<1><<<gb, 256, 0, stream>>>(X, nullptr, Ah, Wt1, b1, nullptr, Hh, (uint8_t*)Hq, N);

  // ---- layer 2: Ah = agg_fp8(Hq); out = (Hh+Ah)@W2+b2 (f32) ----
  agg_kernel<<<aggBlocks, 256, 0, stream>>>(Hq, srcSorted, offdeg, Ah, N);
  gemm_mfma<2><<<gb, 256, 0, stream>>>(nullptr, Hh, Ah, Wt2, b2, out, nullptr, nullptr, N);
}

// Round 9
// 222.349 us; speedup vs baseline: 2.9373x; 1.0644x over previous
//
#include <hip/hip_runtime.h>
#include <hip/hip_bf16.h>
#include <stdint.h>

#define FEATS 128
#define NB_MAX 512        // max buckets (supports N <= 131072)
#define PS_B 1024         // pair-scatter block threads
#define PS_EPT 16         // edges per thread
#define PS_CHUNK (PS_B * PS_EPT)
#define GP 136            // GEMM LDS pitch in shorts (272 B rows: 16B-aligned, 2-way max conflict)

typedef short bf16x8 __attribute__((ext_vector_type(8)));
typedef float f32x4 __attribute__((ext_vector_type(4)));
typedef float f32x2 __attribute__((ext_vector_type(2)));

// ---------------- helpers ----------------

__device__ inline uint32_t f2bf(float f) {  // RTNE f32 -> bf16 (low 16 bits)
  uint32_t x = __float_as_uint(f);
  uint32_t r = ((x >> 16) & 1u) + 0x7fffu;
  return (x + r) >> 16;
}
__device__ inline float bflo(uint32_t u) { return __uint_as_float(u << 16); }
__device__ inline float bfhi(uint32_t u) { return __uint_as_float(u & 0xffff0000u); }

// ---------------- fused: f32->fp8 cast of X + bucket histogram ----------------

__global__ void cast_hist_kernel(const float* __restrict__ X, uint32_t* __restrict__ Xq, int nq,
                                 const int* __restrict__ dst, int* __restrict__ bucketTotal,
                                 int E, int NB) {
  __shared__ int lh[NB_MAX];
  int t = threadIdx.x;
  for (int i = t; i < NB_MAX; i += 256) lh[i] = 0;
  __syncthreads();
  int tid = blockIdx.x * blockDim.x + t;
  int stride = gridDim.x * blockDim.x;
  for (int i = tid; i < nq; i += stride) {  // nq = N*32 (4 feats per u32)
    float4 v = ((const float4*)X)[i];
    uint32_t q = __builtin_amdgcn_cvt_pk_fp8_f32(v.x, v.y, 0, false);
    q = __builtin_amdgcn_cvt_pk_fp8_f32(v.z, v.w, q, true);
    Xq[i] = q;
  }
  for (int i = tid; i < E; i += stride) atomicAdd(&lh[dst[i] >> 8], 1);
  __syncthreads();
  for (int b = t; b < NB; b += 256) {
    int v = lh[b];
    if (v) atomicAdd(&bucketTotal[b], v);
  }
}

// ---------------- bucket scan: exclusive scan of bucket totals ----------------

__global__ void bucket_scan_kernel(const int* __restrict__ bucketTotal, int* __restrict__ bucketBase,
                                   int* __restrict__ bucketCursor, int NB) {
  __shared__ int s[NB_MAX];
  int t = threadIdx.x;
  int v = (t < NB) ? bucketTotal[t] : 0;
  s[t] = v;
  __syncthreads();
  for (int o = 1; o < NB_MAX; o <<= 1) {
    int add = (t >= o) ? s[t - o] : 0;
    __syncthreads();
    s[t] += add;
    __syncthreads();
  }
  if (t < NB) {
    int ex = s[t] - v;
    bucketBase[t] = ex;
    bucketCursor[t] = ex;
    if (t == NB - 1) bucketBase[NB] = s[t];  // = E
  }
}

// ---- pass 2: multisplit packed (src<<8 | dst&255) into dst-page buckets ----
__global__ __launch_bounds__(PS_B) void pairscatter_kernel(const int* __restrict__ src,
                                                           const int* __restrict__ dst,
                                                           int* __restrict__ bucketCursor,
                                                           uint32_t* __restrict__ pairs, int E) {
  __shared__ int hist[NB_MAX];
  __shared__ int rank[NB_MAX];
  __shared__ int res[NB_MAX];
  int t = threadIdx.x;
  int base = blockIdx.x * PS_CHUNK;

  if (t < NB_MAX) {
    hist[t] = 0;
    rank[t] = 0;
  }
  __syncthreads();

  int sr[PS_EPT], dr[PS_EPT];
#pragma unroll
  for (int j = 0; j < PS_EPT; ++j) {
    int i = base + j * PS_B + t;
    if (i < E) {
      sr[j] = src[i];
      dr[j] = dst[i];
      atomicAdd(&hist[dr[j] >> 8], 1);
    } else {
      dr[j] = -1;
    }
  }
  __syncthreads();

  if (t < NB_MAX) {
    int h = hist[t];
    res[t] = h ? atomicAdd(&bucketCursor[t], h) : 0;
  }
  __syncthreads();

#pragma unroll
  for (int j = 0; j < PS_EPT; ++j) {
    if (dr[j] >= 0) {
      int b = dr[j] >> 8;
      int r = atomicAdd(&rank[b], 1);
      pairs[(size_t)(res[b] + r)] = ((uint32_t)sr[j] << 8) | ((uint32_t)dr[j] & 255u);
    }
  }
}

// ---- fused final: per-bucket degree count (LDS) + scan (LDS) + offdeg write + scatter ----
__global__ __launch_bounds__(256) void fused_final_kernel(const uint32_t* __restrict__ pairs,
                                                          const int* __restrict__ bucketBase,
                                                          int2* __restrict__ offdeg,
                                                          int* __restrict__ srcSorted, int N) {
  __shared__ int cnt[256];
  __shared__ int scn[256];
  __shared__ int cur[256];
  int b = blockIdx.x, t = threadIdx.x;
  int bs = bucketBase[b], be = bucketBase[b + 1];
  cnt[t] = 0;
  __syncthreads();
  for (int i = bs + t; i < be; i += 256) atomicAdd(&cnt[pairs[i] & 255u], 1);
  __syncthreads();
  int v = cnt[t];
  scn[t] = v;
  __syncthreads();
  for (int o = 1; o < 256; o <<= 1) {
    int add = (t >= o) ? scn[t - o] : 0;
    __syncthreads();
    scn[t] += add;
    __syncthreads();
  }
  int myoff = bs + scn[t] - v;
  int node = b * 256 + t;
  if (node < N) offdeg[node] = make_int2(myoff, v);
  cur[t] = myoff;
  __syncthreads();
  for (int i = bs + t; i < be; i += 256) {
    uint32_t p = pairs[i];
    int pos = atomicAdd(&cur[p & 255u], 1);
    srcSorted[pos] = (int)(p >> 8);
  }
}

// ---------------- W [K=128][N=128] f32 -> Wt [n][k] bf16 packed (2 matrices, 2 blocks) ----------------

__global__ void wtrans_kernel(const float* __restrict__ W1, const float* __restrict__ W2,
                              uint32_t* __restrict__ Wt1, uint32_t* __restrict__ Wt2) {
  __shared__ uint16_t s[128 * 129];
  const float* W = blockIdx.x ? W2 : W1;
  uint32_t* Wt = blockIdx.x ? Wt2 : Wt1;
  int t = threadIdx.x;
  for (int i = t; i < 16384; i += 256) {
    int k = i >> 7, n = i & 127;
    s[n * 129 + k] = (uint16_t)f2bf(W[i]);
  }
  __syncthreads();
  for (int i = t; i < 8192; i += 256) {
    int n = i >> 6, kd = i & 63;
    uint32_t lo = s[n * 129 + kd * 2];
    uint32_t hi = s[n * 129 + kd * 2 + 1];
    Wt[i] = lo | (hi << 16);
  }
}

// ---- mean aggregation: 16 lanes per node (4 nodes/wave); 4x edge unroll -> 16 gathers in flight ----

__global__ void agg_kernel(const uint32_t* __restrict__ Xq, const int* __restrict__ srcSorted,
                           const int2* __restrict__ offdeg, uint32_t* __restrict__ Ah, int N) {
  int t = threadIdx.x;
  int v = blockIdx.x * 16 + (t >> 4);  // node for this 16-lane group
  int lc = t & 15;                     // 8-feat column group; u32 offset lc*2 within 32-u32 row
  if (v >= N) return;
  int2 od = offdeg[v];
  int start = od.x, d = od.y;
  const int* idxp = srcSorted + start;
  const uint32_t* Xc = Xq + lc * 2;

  f32x2 a0 = {0.f, 0.f}, a1 = {0.f, 0.f}, a2 = {0.f, 0.f}, a3 = {0.f, 0.f};

  int e = 0;
  for (; e + 4 <= d; e += 4) {  // 4 independent gathers in flight per group (16/wave)
    int i0 = idxp[e];
    int i1 = idxp[e + 1];
    int i2 = idxp[e + 2];
    int i3 = idxp[e + 3];
    uint2 ua = *(const uint2*)(Xc + ((size_t)i0 << 5));
    uint2 ub = *(const uint2*)(Xc + ((size_t)i1 << 5));
    uint2 uc = *(const uint2*)(Xc + ((size_t)i2 << 5));
    uint2 ud = *(const uint2*)(Xc + ((size_t)i3 << 5));
    a0 += __builtin_amdgcn_cvt_pk_f32_fp8(ua.x, false);
    a1 += __builtin_amdgcn_cvt_pk_f32_fp8(ua.x, true);
    a2 += __builtin_amdgcn_cvt_pk_f32_fp8(ua.y, false);
    a3 += __builtin_amdgcn_cvt_pk_f32_fp8(ua.y, true);
    a0 += __builtin_amdgcn_cvt_pk_f32_fp8(ub.x, false);
    a1 += __builtin_amdgcn_cvt_pk_f32_fp8(ub.x, true);
    a2 += __builtin_amdgcn_cvt_pk_f32_fp8(ub.y, false);
    a3 += __builtin_amdgcn_cvt_pk_f32_fp8(ub.y, true);
    a0 += __builtin_amdgcn_cvt_pk_f32_fp8(uc.x, false);
    a1 += __builtin_amdgcn_cvt_pk_f32_fp8(uc.x, true);
    a2 += __builtin_amdgcn_cvt_pk_f32_fp8(uc.y, false);
    a3 += __builtin_amdgcn_cvt_pk_f32_fp8(uc.y, true);
    a0 += __builtin_amdgcn_cvt_pk_f32_fp8(ud.x, false);
    a1 += __builtin_amdgcn_cvt_pk_f32_fp8(ud.x, true);
    a2 += __builtin_amdgcn_cvt_pk_f32_fp8(ud.y, false);
    a3 += __builtin_amdgcn_cvt_pk_f32_fp8(ud.y, true);
  }
  for (; e < d; ++e) {  // tail 0..3 edges
    int i0 = idxp[e];
    uint2 ua = *(const uint2*)(Xc + ((size_t)i0 << 5));
    a0 += __builtin_amdgcn_cvt_pk_f32_fp8(ua.x, false);
    a1 += __builtin_amdgcn_cvt_pk_f32_fp8(ua.x, true);
    a2 += __builtin_amdgcn_cvt_pk_f32_fp8(ua.y, false);
    a3 += __builtin_amdgcn_cvt_pk_f32_fp8(ua.y, true);
  }

  float scale = (d > 0) ? (1.0f / (float)d) : 0.0f;
  uint4 o;
  o.x = f2bf(a0.x * scale) | (f2bf(a0.y * scale) << 16);
  o.y = f2bf(a1.x * scale) | (f2bf(a1.y * scale) << 16);
  o.z = f2bf(a2.x * scale) | (f2bf(a2.y * scale) << 16);
  o.w = f2bf(a3.x * scale) | (f2bf(a3.y * scale) << 16);
  *(uint4*)&Ah[(size_t)v * 64 + lc * 4] = o;
}

// ---------------- MFMA GEMM: out = (x + A) @ Wt^T + bias ----------------
// LAYER=1: x from f32 X; writes bf16 h1 (outH) + fp8 h1 (outQ), RELU.
// LAYER=2: x from bf16 Hh; writes f32 d_out.

template <int LAYER>
__global__ __launch_bounds__(256) void gemm_mfma(const float* __restrict__ Xf,
                                                 const uint32_t* __restrict__ Xb,
                                                 const uint32_t* __restrict__ Ab,
                                                 const uint32_t* __restrict__ Wt,
                                                 const float* __restrict__ bias,
                                                 float* __restrict__ outF,
                                                 uint32_t* __restrict__ outH,
                                                 uint8_t* __restrict__ outQ, int N) {
  __shared__ short HS[64 * GP];
  __shared__ short WS[128 * GP];
  int t = threadIdx.x;
  int vbase = blockIdx.x * 64;

  // stage Wt (16B chunks): 2048 chunks of 8 shorts
  for (int c = t; c < 2048; c += 256) {
    int row = c >> 4, col8 = (c & 15) * 8;
    uint4 w = *(const uint4*)&Wt[row * 64 + (col8 >> 1)];
    *(uint4*)&WS[row * GP + col8] = w;
  }
  // stage h = x + A as bf16
  if (LAYER == 1) {
    for (int i = t; i < 2048; i += 256) {  // 64 rows x 32 float4
      int row = i >> 5, c4 = (i & 31) * 4;
      int v = vbase + row;
      uint2 hv = make_uint2(0, 0);
      if (v < N) {
        float4 xv = *(const float4*)&Xf[(size_t)v * FEATS + c4];
        uint2 au = *(const uint2*)&Ab[(size_t)v * 64 + (c4 >> 1)];
        hv.x = f2bf(xv.x + bflo(au.x)) | (f2bf(xv.y + bfhi(au.x)) << 16);
        hv.y = f2bf(xv.z + bflo(au.y)) | (f2bf(xv.w + bfhi(au.y)) << 16);
      }
      *(uint2*)&HS[row * GP + c4] = hv;
    }
  } else {
    for (int i = t; i < 4096; i += 256) {  // 64 rows x 64 dwords
      int row = i >> 6, c = i & 63;
      int v = vbase + row;
      uint32_t hv = 0;
      if (v < N) {
        uint32_t xu = Xb[(size_t)v * 64 + c];
        uint32_t au = Ab[(size_t)v * 64 + c];
        hv = f2bf(bflo(xu) + bflo(au)) | (f2bf(bfhi(xu) + bfhi(au)) << 16);
      }
      *(uint32_t*)&HS[row * GP + c * 2] = hv;
    }
  }
  __syncthreads();

  int wave = t >> 6, l = t & 63;
  int wr = wave * 16;                    // wave's 16 output rows
  int lr = l & 15, lk = (l >> 4) * 8;    // fragment index / k offset

  f32x4 acc[8];
#pragma unroll
  for (int i = 0; i < 8; ++i) acc[i] = (f32x4){0.f, 0.f, 0.f, 0.f};

#pragma unroll
  for (int ks = 0; ks < 4; ++ks) {
    int k0 = ks * 32 + lk;
    bf16x8 a = *(const bf16x8*)&HS[(wr + lr) * GP + k0];
#pragma unroll
    for (int nf = 0; nf < 8; ++nf) {
      bf16x8 b = *(const bf16x8*)&WS[(nf * 16 + lr) * GP + k0];
      acc[nf] = __builtin_amdgcn_mfma_f32_16x16x32_bf16(a, b, acc[nf], 0, 0, 0);
    }
  }

  // epilogue: D col = lane&15, row = (lane>>4)*4 + j
  int orow = wr + (l >> 4) * 4;
#pragma unroll
  for (int nf = 0; nf < 8; ++nf) {
    int col = nf * 16 + lr;
    float bv = bias[col];
#pragma unroll
    for (int j = 0; j < 4; ++j) {
      int v = vbase + orow + j;
      if (v < N) {
        float o = acc[nf][j] + bv;
        if (LAYER == 1) {
          o = fmaxf(o, 0.f);
          ((uint16_t*)outH)[(size_t)v * FEATS + col] = (uint16_t)f2bf(o);
          outQ[(size_t)v * FEATS + col] =
              (uint8_t)(__builtin_amdgcn_cvt_pk_fp8_f32(o, o, 0, false) & 0xffu);
        } else {
          outF[(size_t)v * FEATS + col] = o;
        }
      }
    }
  }
}

// ---------------- launcher ----------------

extern "C" void kernel_launch(void* const* d_in, const int* in_sizes, int n_in,
                              void* d_out, int out_size, void* d_ws, size_t ws_size,
                              hipStream_t stream) {
  const float* X = (const float*)d_in[0];
  const int* src = (const int*)d_in[1];
  const int* dst = (const int*)d_in[2];
  const float* W1 = (const float*)d_in[3];
  const float* b1 = (const float*)d_in[4];
  const float* W2 = (const float*)d_in[5];
  const float* b2 = (const float*)d_in[6];
  float* out = (float*)d_out;

  int N = in_sizes[0] / FEATS;
  int E = in_sizes[1];
  int NB = (N + 255) / 256;  // dst-page buckets

  char* ws = (char*)d_ws;
  auto alloc = [&](size_t bytes) -> char* {
    char* p = ws;
    ws += (bytes + 255) & ~(size_t)255;
    return p;
  };
  int2* offdeg = (int2*)alloc((size_t)N * 8);
  int* bucketTotal = (int*)alloc((size_t)NB_MAX * 4);
  int* bucketBase = (int*)alloc((size_t)(NB_MAX + 1) * 4);
  int* bucketCursor = (int*)alloc((size_t)NB_MAX * 4);
  uint32_t* pairs = (uint32_t*)alloc((size_t)E * 4);
  int* srcSorted = (int*)alloc((size_t)E * 4);
  uint32_t* Xq = (uint32_t*)alloc((size_t)N * 32 * 4);  // fp8 X; becomes fp8 h1 after gemm1 (alias)
  uint32_t* Ah = (uint32_t*)alloc((size_t)N * 64 * 4);  // bf16 aggregate
  uint32_t* Hh = (uint32_t*)alloc((size_t)N * 64 * 4);  // bf16 h1
  uint32_t* Wt1 = (uint32_t*)alloc((size_t)64 * 128 * 4);
  uint32_t* Wt2 = (uint32_t*)alloc((size_t)64 * 128 * 4);
  uint32_t* Hq = Xq;  // safe alias: Xq fully consumed by agg1 before gemm1 writes Hq

  // ---- fused fp8 cast + bucket histogram ----
  hipMemsetAsync(bucketTotal, 0, (size_t)NB_MAX * 4, stream);
  int nq = N * 32;
  cast_hist_kernel<<<512, 256, 0, stream>>>(X, Xq, nq, dst, bucketTotal, E, NB);

  // ---- CSR build (no global per-node atomics anywhere) ----
  bucket_scan_kernel<<<1, NB_MAX, 0, stream>>>(bucketTotal, bucketBase, bucketCursor, NB);
  pairscatter_kernel<<<(E + PS_CHUNK - 1) / PS_CHUNK, PS_B, 0, stream>>>(src, dst, bucketCursor,
                                                                         pairs, E);
  fused_final_kernel<<<NB, 256, 0, stream>>>(pairs, bucketBase, offdeg, srcSorted, N);

  // ---- weight transpose ----
  wtrans_kernel<<<2, 256, 0, stream>>>(W1, W2, Wt1, Wt2);

  int aggBlocks = (N + 15) / 16;
  int gb = (N + 63) / 64;

  // ---- layer 1: Ah = agg_fp8(Xq); Hh/Hq = relu((X+Ah)@W1+b1) ----
  agg_kernel<<<aggBlocks, 256, 0, stream>>>(Xq, srcSorted, offdeg, Ah, N);
  gemm_mfma<1><<<gb, 256, 0, stream>>>(X, nullptr, Ah, Wt1, b1, nullptr, Hh, (uint8_t*)Hq, N);

  // ---- layer 2: Ah = agg_fp8(Hq); out = (Hh+Ah)@W2+b2 (f32) ----
  agg_kernel<<<aggBlocks, 256, 0, stream>>>(Hq, srcSorted, offdeg, Ah, N);
  gemm_mfma<2><<<gb, 256, 0, stream>>>(nullptr, Hh, Ah, Wt2, b2, out, nullptr, nullptr, N);
}